// Round 3
// baseline (706.682 us; speedup 1.0000x reference)
//
#include <hip/hip_runtime.h>
#include <hip/hip_bf16.h>
#include <hip/hip_fp16.h>
#include <math.h>

typedef __attribute__((ext_vector_type(8))) short short8;
typedef __attribute__((ext_vector_type(8))) _Float16 half8;
typedef __attribute__((ext_vector_type(4))) float f32x4;
typedef unsigned short ushort_t;
typedef unsigned long long u64_t;
struct __align__(8) us4 { ushort_t x, y, z, w; };

// round-to-nearest-even fp32 -> bf16
__device__ __forceinline__ ushort_t f2bf(float f) {
    unsigned u = __float_as_uint(f);
    u += 0x7FFFu + ((u >> 16) & 1u);
    return (ushort_t)(u >> 16);
}
__device__ __forceinline__ float bf2f(ushort_t h) {
    return __uint_as_float(((unsigned)h) << 16);
}

__device__ __forceinline__ void store_out(float* p, float v) { *p = v; }
__device__ __forceinline__ void store_out(__half* p, float v) { *p = __float2half(v); }

// ---- detect whether edge_index is int64 (odd int32 words all zero) ----
__global__ void detect64_k(const int* __restrict__ ei, int n_check, int* __restrict__ flag) {
    if (blockIdx.x == 0 && threadIdx.x == 0) {
        int zeros = 0;
        for (int i = 0; i < n_check; ++i) zeros += (ei[2 * i + 1] == 0) ? 1 : 0;
        *flag = (zeros >= n_check - 2) ? 1 : 0;
    }
}

__device__ __forceinline__ void edge_sd(const int* __restrict__ ei, int e, int E,
                                        int is64, int N, int& s_, int& d_) {
    if (e >= E) { s_ = d_ = e - E; return; }   // self-loops appended
    int s, d;
    if (is64) { s = ei[2 * e]; d = ei[2 * (E + e)]; }
    else      { s = ei[e];     d = ei[E + e]; }
    s_ = ((unsigned)s < (unsigned)N) ? s : 0;
    d_ = ((unsigned)d < (unsigned)N) ? d : 0;
}

// ================= CSR construction (2-level counting sort) =================
// Bucket = dst >> 8 (256 nodes/bucket). B = ceil(N/256) <= 512 (N <= 131072).

__global__ __launch_bounds__(256) void csr_hist_k(
    const int* __restrict__ ei, const int* __restrict__ flag,
    int* __restrict__ gtot, int E, int Etot, int N) {
    __shared__ int hc[512];
    int t = threadIdx.x;
    hc[t] = 0; hc[t + 256] = 0;
    __syncthreads();
    int base = blockIdx.x * 4096;
    int is64 = *flag;
    for (int k = 0; k < 16; ++k) {
        int e = base + k * 256 + t;
        if (e < Etot) {
            int s_, d_;
            edge_sd(ei, e, E, is64, N, s_, d_);
            atomicAdd(&hc[d_ >> 8], 1);
        }
    }
    __syncthreads();
    if (hc[t])       atomicAdd(&gtot[t], hc[t]);
    if (hc[t + 256]) atomicAdd(&gtot[t + 256], hc[t + 256]);
}

__global__ void csr_scanb_k(const int* __restrict__ gtot, int* __restrict__ boff,
                            int* __restrict__ gcur, int B) {
    __shared__ int tmp[512];
    int t = threadIdx.x;
    int v = (t < B) ? gtot[t] : 0;
    tmp[t] = v;
    __syncthreads();
    for (int off = 1; off < 512; off <<= 1) {
        int x = (t >= off) ? tmp[t - off] : 0;
        __syncthreads();
        tmp[t] += x;
        __syncthreads();
    }
    if (t < B) {
        int excl = tmp[t] - v;
        boff[t] = excl;
        gcur[t] = excl;
    }
    if (t == B - 1) boff[B] = tmp[t];
}

__global__ __launch_bounds__(256) void csr_stage_k(
    const int* __restrict__ ei, const int* __restrict__ flag,
    int* __restrict__ gcur, u64_t* __restrict__ staging,
    int E, int Etot, int N) {
    __shared__ int bcnt[512];
    __shared__ int resv[512];
    int t = threadIdx.x;
    bcnt[t] = 0; bcnt[t + 256] = 0;
    __syncthreads();
    int base = blockIdx.x * 4096;
    int is64 = *flag;
    u64_t pk[16];
    #pragma unroll
    for (int k = 0; k < 16; ++k) {
        int e = base + k * 256 + t;
        pk[k] = ~0ull;
        if (e < Etot) {
            int s_, d_;
            edge_sd(ei, e, E, is64, N, s_, d_);
            pk[k] = ((u64_t)(unsigned)d_ << 32) | (unsigned)s_;
            atomicAdd(&bcnt[d_ >> 8], 1);
        }
    }
    __syncthreads();
    {
        int c0 = bcnt[t];
        resv[t] = c0 ? atomicAdd(&gcur[t], c0) : 0;
        int c1 = bcnt[t + 256];
        resv[t + 256] = c1 ? atomicAdd(&gcur[t + 256], c1) : 0;
    }
    __syncthreads();
    bcnt[t] = 0; bcnt[t + 256] = 0;   // reuse as within-block rank cursors
    __syncthreads();
    #pragma unroll
    for (int k = 0; k < 16; ++k) {
        if (pk[k] != ~0ull) {
            int b = (int)(pk[k] >> 40);            // dst >> 8
            int pos = resv[b] + atomicAdd(&bcnt[b], 1);
            staging[pos] = pk[k];
        }
    }
}

__global__ __launch_bounds__(256) void csr_fine_k(
    const u64_t* __restrict__ staging, const int* __restrict__ boff,
    int* __restrict__ rowptr, int* __restrict__ csr_src, int N, int Etot) {
    __shared__ int hcnt[256];
    __shared__ int scn[256];
    const int b = blockIdx.x, t = threadIdx.x;
    const int lo = b << 8;
    const int base = boff[b], cnt = boff[b + 1] - base;
    hcnt[t] = 0;
    __syncthreads();
    for (int i = t; i < cnt; i += 256) {
        int dst = (int)(staging[base + i] >> 32);
        atomicAdd(&hcnt[dst - lo], 1);
    }
    __syncthreads();
    int v = hcnt[t];
    scn[t] = v;
    __syncthreads();
    for (int off = 1; off < 256; off <<= 1) {
        int x = (t >= off) ? scn[t - off] : 0;
        __syncthreads();
        scn[t] += x;
        __syncthreads();
    }
    int excl = scn[t] - v;
    if (lo + t < N) rowptr[lo + t] = base + excl;
    hcnt[t] = base + excl;   // reuse as cursor
    __syncthreads();
    for (int i = t; i < cnt; i += 256) {
        u64_t pd = staging[base + i];
        int dst = (int)(pd >> 32);
        int pos = atomicAdd(&hcnt[dst - lo], 1);
        csr_src[pos] = (int)(pd & 0xFFFFFFFFu);
    }
    if (b == 0 && t == 0) rowptr[N] = Etot;
}

// ===== weight pre-split (transposed [n][k], zero-padded to Mp rows) =====
__global__ void splitw_bf16_k(const float* __restrict__ W, ushort_t* __restrict__ Wh,
                              ushort_t* __restrict__ Wl, int K, int M, int Mp) {
    int i = blockIdx.x * 256 + threadIdx.x;
    if (i >= Mp * K) return;
    int n = i / K, k = i - n * K;
    float v = (n < M) ? W[(size_t)k * M + n] : 0.f;
    ushort_t h = f2bf(v);
    Wh[i] = h;
    Wl[i] = f2bf(v - bf2f(h));
}

__global__ void splitw_f16_k(const float* __restrict__ W, ushort_t* __restrict__ Wh,
                             ushort_t* __restrict__ Wl, int K, int M, int Mp) {
    int i = blockIdx.x * 256 + threadIdx.x;
    if (i >= Mp * K) return;
    int n = i / K, k = i - n * K;
    float v = (n < M) ? W[(size_t)k * M + n] : 0.f;
    __half h = __float2half(v);
    Wh[i] = __half_as_ushort(h);
    Wl[i] = __half_as_ushort(__float2half(v - __half2float(h)));
}

// ================= split-bf16 MFMA GEMM (fp32 A; layer 0) =================
// B pre-split/transposed: BhT/BlT [Mp][K] bf16 bits.
template <int BN, int WMCNT, int WNCNT, typename TOUT, int LMODE>
__global__ __launch_bounds__(256) void mfma_gemm_k(const float* __restrict__ A,
                                                   const ushort_t* __restrict__ BhT,
                                                   const ushort_t* __restrict__ BlT,
                                                   TOUT* __restrict__ C,
                                                   int N, int K, int M,
                                                   const float* __restrict__ a_s,
                                                   const float* __restrict__ a_d,
                                                   float* __restrict__ alS,
                                                   float* __restrict__ alD) {
    constexpr int BM = 128;
    constexpr int PAD = 40;
    constexpr int WMX = BM / WMCNT;
    constexpr int WNX = BN / WNCNT;
    constexpr int FM = WMX / 16, FN = WNX / 16;
    static_assert(FN == 4, "logit epilogue assumes WNX==64");

    __shared__ ushort_t Ah[BM * PAD], Al[BM * PAD];
    __shared__ ushort_t Bh[BN * PAD], Bl[BN * PAD];

    const int tx = threadIdx.x;
    const int wave = tx >> 6, lane = tx & 63;
    const int quad = lane >> 4, l16 = lane & 15;
    const int br = blockIdx.y * BM, bc = blockIdx.x * BN;
    const int wm = (wave / WNCNT) * WMX;
    const int wn = (wave % WNCNT) * WNX;

    f32x4 acc[FM][FN] = {};

    for (int k0 = 0; k0 < K; k0 += 32) {
        #pragma unroll
        for (int r = 0; r < 4; ++r) {
            int i = r * 256 + tx;
            int m = i >> 3, k4 = (i & 7) * 4;
            int gr = br + m;
            float4 v = make_float4(0.f, 0.f, 0.f, 0.f);
            if (gr < N) v = *(const float4*)&A[(size_t)gr * K + k0 + k4];
            us4 h, l;
            h.x = f2bf(v.x); l.x = f2bf(v.x - bf2f(h.x));
            h.y = f2bf(v.y); l.y = f2bf(v.y - bf2f(h.y));
            h.z = f2bf(v.z); l.z = f2bf(v.z - bf2f(h.z));
            h.w = f2bf(v.w); l.w = f2bf(v.w - bf2f(h.w));
            *(us4*)&Ah[m * PAD + k4] = h;
            *(us4*)&Al[m * PAD + k4] = l;
        }
        // B staging: pure 16B copies from pre-split transposed weights
        #pragma unroll
        for (int r = 0; r < BN / 64; ++r) {
            int i = r * 256 + tx;
            int n = i >> 2, k8 = (i & 3) * 8;
            *(short8*)&Bh[n * PAD + k8] = *(const short8*)&BhT[(size_t)(bc + n) * K + k0 + k8];
            *(short8*)&Bl[n * PAD + k8] = *(const short8*)&BlT[(size_t)(bc + n) * K + k0 + k8];
        }
        __syncthreads();

        short8 afh[FM], afl[FM];
        #pragma unroll
        for (int mi = 0; mi < FM; ++mi) {
            int row = wm + mi * 16 + l16;
            afh[mi] = *(const short8*)&Ah[row * PAD + quad * 8];
            afl[mi] = *(const short8*)&Al[row * PAD + quad * 8];
        }
        #pragma unroll
        for (int ni = 0; ni < FN; ++ni) {
            int row = wn + ni * 16 + l16;
            short8 bfh = *(const short8*)&Bh[row * PAD + quad * 8];
            short8 bfl = *(const short8*)&Bl[row * PAD + quad * 8];
            #pragma unroll
            for (int mi = 0; mi < FM; ++mi) {
                acc[mi][ni] = __builtin_amdgcn_mfma_f32_16x16x32_bf16(afh[mi], bfh, acc[mi][ni], 0, 0, 0);
                acc[mi][ni] = __builtin_amdgcn_mfma_f32_16x16x32_bf16(afh[mi], bfl, acc[mi][ni], 0, 0, 0);
                acc[mi][ni] = __builtin_amdgcn_mfma_f32_16x16x32_bf16(afl[mi], bfh, acc[mi][ni], 0, 0, 0);
            }
        }
        __syncthreads();
    }

    #pragma unroll
    for (int mi = 0; mi < FM; ++mi) {
        #pragma unroll
        for (int ni = 0; ni < FN; ++ni) {
            int gc = bc + wn + ni * 16 + l16;
            if (gc >= M) continue;
            #pragma unroll
            for (int r = 0; r < 4; ++r) {
                int gr = br + wm + mi * 16 + quad * 4 + r;
                if (gr < N) store_out(&C[(size_t)gr * M + gc], acc[mi][ni][r]);
            }
        }
    }

    // ---- fused logits ----
    float aSv[FN], aDv[FN];
    #pragma unroll
    for (int ni = 0; ni < FN; ++ni) {
        int gc = bc + wn + ni * 16 + l16;
        bool ok = gc < M;
        aSv[ni] = ok ? a_s[gc] : 0.f;
        aDv[ni] = ok ? a_d[gc] : 0.f;
    }
    if (LMODE == 1) {
        #pragma unroll
        for (int mi = 0; mi < FM; ++mi) {
            #pragma unroll
            for (int r = 0; r < 4; ++r) {
                float p1a = acc[mi][0][r] * aSv[0] + acc[mi][1][r] * aSv[1];
                float p1b = acc[mi][2][r] * aSv[2] + acc[mi][3][r] * aSv[3];
                float p2a = acc[mi][0][r] * aDv[0] + acc[mi][1][r] * aDv[1];
                float p2b = acc[mi][2][r] * aDv[2] + acc[mi][3][r] * aDv[3];
                #pragma unroll
                for (int off = 1; off < 16; off <<= 1) {
                    p1a += __shfl_xor(p1a, off);
                    p1b += __shfl_xor(p1b, off);
                    p2a += __shfl_xor(p2a, off);
                    p2b += __shfl_xor(p2b, off);
                }
                if (l16 == 0) {
                    int gr = br + wm + mi * 16 + quad * 4 + r;
                    if (gr < N) {
                        int hb = (bc + wn) >> 5;
                        alS[gr * 8 + hb]     = p1a;
                        alS[gr * 8 + hb + 1] = p1b;
                        alD[gr * 8 + hb]     = p2a;
                        alD[gr * 8 + hb + 1] = p2b;
                    }
                }
            }
        }
    } else {
        #pragma unroll
        for (int mi = 0; mi < FM; ++mi) {
            #pragma unroll
            for (int r = 0; r < 4; ++r) {
                float p1 = acc[mi][0][r] * aSv[0] + acc[mi][1][r] * aSv[1]
                         + acc[mi][2][r] * aSv[2] + acc[mi][3][r] * aSv[3];
                float p2 = acc[mi][0][r] * aDv[0] + acc[mi][1][r] * aDv[1]
                         + acc[mi][2][r] * aDv[2] + acc[mi][3][r] * aDv[3];
                #pragma unroll
                for (int off = 1; off < 16; off <<= 1) {
                    p1 += __shfl_xor(p1, off);
                    p2 += __shfl_xor(p2, off);
                }
                if (l16 == 0) {
                    int gr = br + wm + mi * 16 + quad * 4 + r;
                    if (gr < N) { alS[gr] = p1; alD[gr] = p2; }
                }
            }
        }
    }
}

// ======== fp16-A 2-pass MFMA GEMM (layers 1/2): A fp16, B pre-split fp16 hi/lo ========
template <int BN, int WMCNT, int WNCNT, typename TOUT, int LMODE>
__global__ __launch_bounds__(256) void mfma_gemm_f16_k(const __half* __restrict__ A,
                                                       const ushort_t* __restrict__ BhT,
                                                       const ushort_t* __restrict__ BlT,
                                                       TOUT* __restrict__ C,
                                                       int N, int K, int M,
                                                       const float* __restrict__ a_s,
                                                       const float* __restrict__ a_d,
                                                       float* __restrict__ alS,
                                                       float* __restrict__ alD) {
    constexpr int BM = 128;
    constexpr int PAD = 40;
    constexpr int WMX = BM / WMCNT;
    constexpr int WNX = BN / WNCNT;
    constexpr int FM = WMX / 16, FN = WNX / 16;
    static_assert(FN == 4, "logit epilogue assumes WNX==64");

    __shared__ ushort_t Ah[BM * PAD];
    __shared__ ushort_t Bh[BN * PAD], Bl[BN * PAD];

    const int tx = threadIdx.x;
    const int wave = tx >> 6, lane = tx & 63;
    const int quad = lane >> 4, l16 = lane & 15;
    const int br = blockIdx.y * BM, bc = blockIdx.x * BN;
    const int wm = (wave / WNCNT) * WMX;
    const int wn = (wave % WNCNT) * WNX;

    f32x4 acc[FM][FN] = {};

    for (int k0 = 0; k0 < K; k0 += 32) {
        #pragma unroll
        for (int r = 0; r < 2; ++r) {
            int i = r * 256 + tx;
            int m = i >> 2, k8 = (i & 3) * 8;
            int gr = br + m;
            short8 v = {};
            if (gr < N) v = *(const short8*)&A[(size_t)gr * K + k0 + k8];
            *(short8*)&Ah[m * PAD + k8] = v;
        }
        #pragma unroll
        for (int r = 0; r < BN / 64; ++r) {
            int i = r * 256 + tx;
            int n = i >> 2, k8 = (i & 3) * 8;
            *(short8*)&Bh[n * PAD + k8] = *(const short8*)&BhT[(size_t)(bc + n) * K + k0 + k8];
            *(short8*)&Bl[n * PAD + k8] = *(const short8*)&BlT[(size_t)(bc + n) * K + k0 + k8];
        }
        __syncthreads();

        half8 af[FM];
        #pragma unroll
        for (int mi = 0; mi < FM; ++mi) {
            int row = wm + mi * 16 + l16;
            af[mi] = *(const half8*)&Ah[row * PAD + quad * 8];
        }
        #pragma unroll
        for (int ni = 0; ni < FN; ++ni) {
            int row = wn + ni * 16 + l16;
            half8 bfh = *(const half8*)&Bh[row * PAD + quad * 8];
            half8 bfl = *(const half8*)&Bl[row * PAD + quad * 8];
            #pragma unroll
            for (int mi = 0; mi < FM; ++mi) {
                acc[mi][ni] = __builtin_amdgcn_mfma_f32_16x16x32_f16(af[mi], bfh, acc[mi][ni], 0, 0, 0);
                acc[mi][ni] = __builtin_amdgcn_mfma_f32_16x16x32_f16(af[mi], bfl, acc[mi][ni], 0, 0, 0);
            }
        }
        __syncthreads();
    }

    #pragma unroll
    for (int mi = 0; mi < FM; ++mi) {
        #pragma unroll
        for (int ni = 0; ni < FN; ++ni) {
            int gc = bc + wn + ni * 16 + l16;
            if (gc >= M) continue;
            #pragma unroll
            for (int r = 0; r < 4; ++r) {
                int gr = br + wm + mi * 16 + quad * 4 + r;
                if (gr < N) store_out(&C[(size_t)gr * M + gc], acc[mi][ni][r]);
            }
        }
    }

    // ---- fused logits ----
    float aSv[FN], aDv[FN];
    #pragma unroll
    for (int ni = 0; ni < FN; ++ni) {
        int gc = bc + wn + ni * 16 + l16;
        bool ok = gc < M;
        aSv[ni] = ok ? a_s[gc] : 0.f;
        aDv[ni] = ok ? a_d[gc] : 0.f;
    }
    if (LMODE == 1) {
        #pragma unroll
        for (int mi = 0; mi < FM; ++mi) {
            #pragma unroll
            for (int r = 0; r < 4; ++r) {
                float p1a = acc[mi][0][r] * aSv[0] + acc[mi][1][r] * aSv[1];
                float p1b = acc[mi][2][r] * aSv[2] + acc[mi][3][r] * aSv[3];
                float p2a = acc[mi][0][r] * aDv[0] + acc[mi][1][r] * aDv[1];
                float p2b = acc[mi][2][r] * aDv[2] + acc[mi][3][r] * aDv[3];
                #pragma unroll
                for (int off = 1; off < 16; off <<= 1) {
                    p1a += __shfl_xor(p1a, off);
                    p1b += __shfl_xor(p1b, off);
                    p2a += __shfl_xor(p2a, off);
                    p2b += __shfl_xor(p2b, off);
                }
                if (l16 == 0) {
                    int gr = br + wm + mi * 16 + quad * 4 + r;
                    if (gr < N) {
                        int hb = (bc + wn) >> 5;
                        alS[gr * 8 + hb]     = p1a;
                        alS[gr * 8 + hb + 1] = p1b;
                        alD[gr * 8 + hb]     = p2a;
                        alD[gr * 8 + hb + 1] = p2b;
                    }
                }
            }
        }
    } else {
        #pragma unroll
        for (int mi = 0; mi < FM; ++mi) {
            #pragma unroll
            for (int r = 0; r < 4; ++r) {
                float p1 = acc[mi][0][r] * aSv[0] + acc[mi][1][r] * aSv[1]
                         + acc[mi][2][r] * aSv[2] + acc[mi][3][r] * aSv[3];
                float p2 = acc[mi][0][r] * aDv[0] + acc[mi][1][r] * aDv[1]
                         + acc[mi][2][r] * aDv[2] + acc[mi][3][r] * aDv[3];
                #pragma unroll
                for (int off = 1; off < 16; off <<= 1) {
                    p1 += __shfl_xor(p1, off);
                    p2 += __shfl_xor(p2, off);
                }
                if (l16 == 0) {
                    int gr = br + wm + mi * 16 + quad * 4 + r;
                    if (gr < N) { alS[gr] = p1; alD[gr] = p2; }
                }
            }
        }
    }
}

// ================= fused per-node softmax + aggregation =================
// H=8, C=32. One wave per node.
// R2: pipeline depth 4 -> 8. FETCH_SIZE is at ~92% of the per-XCD compulsory
// floor (51.2MB table x 8 XCDs), so the lever is RATE not BYTES: double the
// outstanding 16B gathers per lane (Little's law on ~700ns LLC latency).
// rq[8]+a2q[8] adds ~20 VGPR; stays within the 64-VGPR/8-waves-per-SIMD bin.
__global__ __launch_bounds__(256) void node_aggr8_k(
    const int* __restrict__ rowptr, const int* __restrict__ csr_src,
    const float* __restrict__ alS, const float* __restrict__ alD,
    const __half* __restrict__ xh, const float* __restrict__ bias,
    __half* __restrict__ out, int N, int do_elu) {
    __shared__ int    lsrc[4][64];
    __shared__ __half lalpha[4][64 * 8];
    const int wv = threadIdx.x >> 6;
    int wid = (blockIdx.x * 256 + threadIdx.x) >> 6;
    int lane = threadIdx.x & 63;
    if (wid >= N) return;
    const int d = wid;
    const int beg = rowptr[d], end = rowptr[d + 1];
    const int deg = end - beg;
    const int dcap = deg < 64 ? deg : 64;

    const int h = lane & 7, esub = lane >> 3;
    const float aDh = alD[d * 8 + h];

    const int nch = (deg + 7) >> 3;

    // sweep 1: exp sums; exp values stay in registers (static-indexed unroll)
    float exv[8] = {};
    float s = 0.f;
    #pragma unroll
    for (int c = 0; c < 8; ++c) {
        int sl = c * 8 + esub;
        int e = beg + sl;
        if (e < end) {
            int src = csr_src[e];
            float ev = alS[src * 8 + h] + aDh;
            ev = ev > 0.f ? ev : 0.2f * ev;
            float ex = __expf(fminf(ev, 30.f));
            if (h == 0) lsrc[wv][sl] = src;
            exv[c] = ex;
            s += ex;
        }
    }
    for (int c = 8; c < nch; ++c) {      // overflow (deg>64): sum only
        int e = beg + c * 8 + esub;
        if (e < end) {
            int src = csr_src[e];
            float ev = alS[src * 8 + h] + aDh;
            ev = ev > 0.f ? ev : 0.2f * ev;
            s += __expf(fminf(ev, 30.f));
        }
    }
    #pragma unroll
    for (int off = 8; off < 64; off <<= 1) s += __shfl_xor(s, off);

    // pre-scaled fp16 alpha into LDS (lane's own head h, so 1/s is local)
    float rsl = 1.f / s;
    #pragma unroll
    for (int c = 0; c < 8; ++c) {
        int sl = c * 8 + esub;
        if (sl < dcap) lalpha[wv][sl * 8 + h] = __float2half(exv[c] * rsl);
    }

    const int g = lane & 31;              // channel group: channels g*8..g*8+7
    const int hh = g >> 2;                // head of this channel group
    const int p = lane >> 5;              // edge parity
    const float rs = __shfl(rsl, hh);     // only needed by the overflow path

    const char* xb = (const char*)xh;
    const unsigned goff = (unsigned)(g << 4);   // byte offset within a 512B row

    const int T = (dcap + 1) >> 1;        // pair-steps over cached edges (T>=1)
    __half2 a2q[8];
    float4 rq[8];
    __half2 hacc[4] = {};

    // prologue: stages 0..7 (clamped addresses are always valid; alpha zeroed)
    #pragma unroll
    for (int i = 0; i < 8; ++i) {
        int e0 = 2 * i + p;
        int idx = e0 < dcap ? e0 : dcap - 1;
        int sv = lsrc[wv][idx];
        ushort_t ub = __half_as_ushort(lalpha[wv][idx * 8 + hh]);
        if (e0 >= dcap) ub = 0;
        a2q[i] = __half2half2(__ushort_as_half(ub));
        rq[i] = *(const float4*)(xb + (((unsigned)sv << 9) + goff));
    }

    #define PROC8(i)                                                        \
    {                                                                       \
        float4 raw = rq[i];                                                 \
        __half2 a2 = a2q[i];                                                \
        int e0 = 2 * (t + 8 + (i)) + p;                                     \
        ushort_t ub = 0;                                                    \
        if (e0 < dcap) {                                                    \
            int srcn = lsrc[wv][e0];                                        \
            ub = __half_as_ushort(lalpha[wv][e0 * 8 + hh]);                 \
            rq[i] = *(const float4*)(xb + (((unsigned)srcn << 9) + goff));  \
        }                                                                   \
        a2q[i] = __half2half2(__ushort_as_half(ub));                        \
        const __half2* hp = (const __half2*)&raw;                           \
        hacc[0] = __hfma2(hp[0], a2, hacc[0]);                              \
        hacc[1] = __hfma2(hp[1], a2, hacc[1]);                              \
        hacc[2] = __hfma2(hp[2], a2, hacc[2]);                              \
        hacc[3] = __hfma2(hp[3], a2, hacc[3]);                              \
    }
    #define TAIL8(i)                                                        \
    {                                                                       \
        float4 raw = rq[i];                                                 \
        __half2 a2 = a2q[i];                                                \
        const __half2* hp = (const __half2*)&raw;                           \
        hacc[0] = __hfma2(hp[0], a2, hacc[0]);                              \
        hacc[1] = __hfma2(hp[1], a2, hacc[1]);                              \
        hacc[2] = __hfma2(hp[2], a2, hacc[2]);                              \
        hacc[3] = __hfma2(hp[3], a2, hacc[3]);                              \
    }
    int t = 0;
    for (; t + 8 <= T; t += 8) {
        PROC8(0) PROC8(1) PROC8(2) PROC8(3) PROC8(4) PROC8(5) PROC8(6) PROC8(7)
    }
    {
        int rem = T - t;   // 0..7, wave-uniform
        if (rem > 0) { TAIL8(0)
        if (rem > 1) { TAIL8(1)
        if (rem > 2) { TAIL8(2)
        if (rem > 3) { TAIL8(3)
        if (rem > 4) { TAIL8(4)
        if (rem > 5) { TAIL8(5)
        if (rem > 6) { TAIL8(6) } } } } } } }
    }
    #undef PROC8
    #undef TAIL8

    // overflow gather (deg>64): recompute path, 2 edges/step via shuffles
    for (int c = 8; c < nch; ++c) {
        int base = beg + c * 8;
        int e = base + esub;
        int src_l = 0; float ex_l = 0.f;
        if (e < end) {
            src_l = csr_src[e];
            float ev = alS[src_l * 8 + h] + aDh;
            ev = ev > 0.f ? ev : 0.2f * ev;
            ex_l = __expf(fminf(ev, 30.f));
        }
        int cnt = end - base; if (cnt > 8) cnt = 8;
        int steps = (cnt + 1) >> 1;
        for (int t2 = 0; t2 < steps; ++t2) {
            int j = t2 * 2 + p;
            int jc = j < cnt ? j : (cnt - 1);
            int src = __shfl(src_l, jc * 8);
            float af = __shfl(ex_l, jc * 8 + hh) * rs;
            if (j >= cnt) af = 0.f;
            __half2 a2 = __float2half2_rn(af);
            const float4 raw = *(const float4*)(xb + (((unsigned)src << 9) + goff));
            const __half2* hp = (const __half2*)&raw;
            hacc[0] = __hfma2(hp[0], a2, hacc[0]);
            hacc[1] = __hfma2(hp[1], a2, hacc[1]);
            hacc[2] = __hfma2(hp[2], a2, hacc[2]);
            hacc[3] = __hfma2(hp[3], a2, hacc[3]);
        }
    }

    // merge parity halves (lane ^ 32)
    #pragma unroll
    for (int k = 0; k < 4; ++k) {
        int vi = __shfl_xor(*(int*)&hacc[k], 32);
        hacc[k] = __hadd2(hacc[k], *(__half2*)&vi);
    }

    if (p == 0) {
        float2 f0 = __half22float2(hacc[0]);
        float2 f1 = __half22float2(hacc[1]);
        float2 f2 = __half22float2(hacc[2]);
        float2 f3 = __half22float2(hacc[3]);
        const float4 bv0 = *(const float4*)&bias[g * 8];
        const float4 bv1 = *(const float4*)&bias[g * 8 + 4];
        float o[8];
        o[0] = f0.x + bv0.x; o[1] = f0.y + bv0.y;
        o[2] = f1.x + bv0.z; o[3] = f1.y + bv0.w;
        o[4] = f2.x + bv1.x; o[5] = f2.y + bv1.y;
        o[6] = f3.x + bv1.z; o[7] = f3.y + bv1.w;
        if (do_elu) {
            #pragma unroll
            for (int k = 0; k < 8; ++k) o[k] = o[k] > 0.f ? o[k] : (__expf(o[k]) - 1.f);
        }
        float4 st;
        ((__half2*)&st)[0] = __floats2half2_rn(o[0], o[1]);
        ((__half2*)&st)[1] = __floats2half2_rn(o[2], o[3]);
        ((__half2*)&st)[2] = __floats2half2_rn(o[4], o[5]);
        ((__half2*)&st)[3] = __floats2half2_rn(o[6], o[7]);
        *(float4*)(out + ((size_t)d << 8) + g * 8) = st;
    }
}

// H=1, C=40. One wave per node. R2: pipeline depth 4 -> 8 (same rationale).
__global__ __launch_bounds__(256) void node_aggr1_k(
    const int* __restrict__ rowptr, const int* __restrict__ csr_src,
    const float* __restrict__ alS, const float* __restrict__ alD,
    const __half* __restrict__ xh2, const float* __restrict__ bias,
    float* __restrict__ out, int N) {
    __shared__ int   lsrc1[4][64];
    __shared__ float lal1[4][64];
    const int wv = threadIdx.x >> 6;
    int wid = (blockIdx.x * 256 + threadIdx.x) >> 6;
    int lane = threadIdx.x & 63;
    if (wid >= N) return;
    const int d = wid;
    const int beg = rowptr[d], end = rowptr[d + 1];
    const int deg = end - beg;
    const int dcap = deg < 64 ? deg : 64;
    const float aD = alD[d];

    float ex0 = 0.f;
    {
        int e = beg + lane;
        if (e < end) {
            int src0 = csr_src[e];
            float ev = alS[src0] + aD;
            ev = ev > 0.f ? ev : 0.2f * ev;
            ex0 = __expf(fminf(ev, 30.f));
            lsrc1[wv][lane] = src0;
        }
    }
    float s = ex0;
    for (int e = beg + 64 + lane; e < end; e += 64) {
        int src = csr_src[e];
        float ev = alS[src] + aD;
        ev = ev > 0.f ? ev : 0.2f * ev;
        s += __expf(fminf(ev, 30.f));
    }
    #pragma unroll
    for (int off = 1; off < 64; off <<= 1) s += __shfl_xor(s, off);
    const float rs = 1.f / s;
    if (lane < dcap) lal1[wv][lane] = ex0 * rs;

    const int q = lane & 31;              // channel pair: channels q*2, q*2+1
    const int p = lane >> 5;              // edge parity
    const int qg = q < 20 ? q : 19;       // clamp idle lanes inside the 80B row
    const unsigned qb = (unsigned)(qg << 2);
    const char* xb2 = (const char*)xh2;

    const int T = (dcap + 1) >> 1;
    float alq[8];
    __half2 rq1[8];
    float ax = 0.f, ay = 0.f;

    #pragma unroll
    for (int i = 0; i < 8; ++i) {
        int e0 = 2 * i + p;
        int idx = e0 < dcap ? e0 : dcap - 1;
        int sv = lsrc1[wv][idx];
        float av = lal1[wv][idx];
        alq[i] = e0 < dcap ? av : 0.f;
        rq1[i] = *(const __half2*)(xb2 + ((unsigned)sv * 80u + qb));
    }

    #define PROC1(i)                                                        \
    {                                                                       \
        float2 rf = __half22float2(rq1[i]);                                 \
        float al = alq[i];                                                  \
        int e0 = 2 * (t + 8 + (i)) + p;                                     \
        float an = 0.f;                                                     \
        if (e0 < dcap) {                                                    \
            int sv = lsrc1[wv][e0];                                         \
            an = lal1[wv][e0];                                              \
            rq1[i] = *(const __half2*)(xb2 + ((unsigned)sv * 80u + qb));    \
        }                                                                   \
        alq[i] = an;                                                        \
        ax += rf.x * al; ay += rf.y * al;                                   \
    }
    #define TAIL1(i)                                                        \
    {                                                                       \
        float2 rf = __half22float2(rq1[i]);                                 \
        ax += rf.x * alq[i]; ay += rf.y * alq[i];                           \
    }
    int t = 0;
    for (; t + 8 <= T; t += 8) {
        PROC1(0) PROC1(1) PROC1(2) PROC1(3) PROC1(4) PROC1(5) PROC1(6) PROC1(7)
    }
    {
        int rem = T - t;
        if (rem > 0) { TAIL1(0)
        if (rem > 1) { TAIL1(1)
        if (rem > 2) { TAIL1(2)
        if (rem > 3) { TAIL1(3)
        if (rem > 4) { TAIL1(4)
        if (rem > 5) { TAIL1(5)
        if (rem > 6) { TAIL1(6) } } } } } } }
    }
    #undef PROC1
    #undef TAIL1

    // overflow (deg > 64): refill LDS per 64-edge chunk, simple paired loop
    for (int eb = beg + 64; eb < end; eb += 64) {
        int e = eb + lane;
        int cnt = end - eb; if (cnt > 64) cnt = 64;
        if (e < end) {
            int srcl = csr_src[e];
            float ev = alS[srcl] + aD;
            ev = ev > 0.f ? ev : 0.2f * ev;
            lsrc1[wv][lane] = srcl;
            lal1[wv][lane] = __expf(fminf(ev, 30.f)) * rs;
        }
        int T2 = (cnt + 1) >> 1;
        for (int t2 = 0; t2 < T2; ++t2) {
            int e0 = 2 * t2 + p;
            float al = 0.f;
            int sv = lsrc1[wv][0];
            if (e0 < cnt) { sv = lsrc1[wv][e0]; al = lal1[wv][e0]; }
            float2 rf = __half22float2(*(const __half2*)(xb2 + ((unsigned)sv * 80u + qb)));
            ax += rf.x * al; ay += rf.y * al;
        }
    }

    // merge parity halves
    ax += __shfl_xor(ax, 32);
    ay += __shfl_xor(ay, 32);

    if (p == 0 && q < 20) {
        float2 bv = *(const float2*)&bias[q * 2];
        float2 st = make_float2(ax + bv.x, ay + bv.y);
        *(float2*)&out[(size_t)d * 40 + q * 2] = st;
    }
}

extern "C" void kernel_launch(void* const* d_in, const int* in_sizes, int n_in,
                              void* d_out, int out_size, void* d_ws, size_t ws_size,
                              hipStream_t stream) {
    const float* feat = (const float*)d_in[0];
    const int*   ei   = (const int*)d_in[1];
    const float* W0   = (const float*)d_in[2];
    const float* a0s  = (const float*)d_in[3];
    const float* a0d  = (const float*)d_in[4];
    const float* b0   = (const float*)d_in[5];
    const float* W1   = (const float*)d_in[6];
    const float* a1s  = (const float*)d_in[7];
    const float* a1d  = (const float*)d_in[8];
    const float* b1   = (const float*)d_in[9];
    const float* W2   = (const float*)d_in[10];
    const float* a2s  = (const float*)d_in[11];
    const float* a2d  = (const float*)d_in[12];
    const float* b2   = (const float*)d_in[13];
    float* out = (float*)d_out;

    const int N = in_sizes[0] / 128;   // 100000
    const int E = in_sizes[1] / 2;     // 1600000
    const int Etot = E + N;

    // workspace layout (~112 MB total)
    __half* hbuf = (__half*)d_ws;                     // N*256 fp16 (aggr out / gemm A)
    __half* xh   = hbuf + (size_t)N * 256;            // N*256 fp16 (gemm out; CSR staging alias)
    __half* x2h  = xh + (size_t)N * 256;              // N*40 fp16 (layer-2 gemm out)
    float*  alS  = (float*)(x2h + (size_t)N * 40);    // N*8
    float*  alD  = alS + (size_t)N * 8;               // N*8
    int* rowptr   = (int*)(alD + (size_t)N * 8);      // N+1
    int* gtot     = rowptr + N + 1;                   // 512 (bucket counts)
    int* boff     = gtot + 512;                       // 513 (bucket offsets)
    int* gcur     = boff + 513;                       // 512 (bucket cursors)
    int* csr_src  = gcur + 512;                       // Etot
    int* flag     = csr_src + Etot;                   // 1
    // pre-split transposed weights (16B aligned)
    uintptr_t wsp = ((uintptr_t)(flag + 1) + 15) & ~(uintptr_t)15;
    ushort_t* w0h = (ushort_t*)wsp;                   // 256*128
    ushort_t* w0l = w0h + 256 * 128;
    ushort_t* w1h = w0l + 256 * 128;                  // 256*256
    ushort_t* w1l = w1h + 256 * 256;
    ushort_t* w2h = w1l + 256 * 256;                  // 64*256
    ushort_t* w2l = w2h + 64 * 256;

    // CSR staging (dead once csr_fine_k completes; aliases xh which is first
    // written by the layer-0 GEMM afterwards — stream-ordered, no hazard)
    u64_t* staging = (u64_t*)xh;                      // Etot * 8B <= 13.7MB < 51.2MB

    const int B     = (N + 255) >> 8;                 // buckets of 256 nodes (<=512)
    const int nb_e4 = (Etot + 4095) / 4096;           // hist/stage grid
    const int nb_nw = (N + 3) / 4;

    // ---- CSR build (counting sort) + weight pre-split ----
    detect64_k<<<1, 1, 0, stream>>>(ei, 512, flag);
    hipMemsetAsync(gtot, 0, 512 * 4, stream);
    csr_hist_k<<<nb_e4, 256, 0, stream>>>(ei, flag, gtot, E, Etot, N);
    csr_scanb_k<<<1, 512, 0, stream>>>(gtot, boff, gcur, B);
    csr_stage_k<<<nb_e4, 256, 0, stream>>>(ei, flag, gcur, staging, E, Etot, N);
    csr_fine_k<<<B, 256, 0, stream>>>(staging, boff, rowptr, csr_src, N, Etot);
    splitw_bf16_k<<<128, 256, 0, stream>>>(W0, w0h, w0l, 128, 256, 256);
    splitw_f16_k<<<256, 256, 0, stream>>>(W1, w1h, w1l, 256, 256, 256);
    splitw_f16_k<<<64, 256, 0, stream>>>(W2, w2h, w2l, 256, 40, 64);

    const int mb = (N + 127) / 128;

    // ---------- Layer 0: Fin=128, H=8, C=32 (fp32 A, 3-pass bf16, fused logits) ----------
    mfma_gemm_k<128, 2, 2, __half, 1><<<dim3(2, mb), 256, 0, stream>>>(
        feat, w0h, w0l, xh, N, 128, 256, a0s, a0d, alS, alD);
    node_aggr8_k<<<nb_nw, 256, 0, stream>>>(rowptr, csr_src, alS, alD, xh, b0,
                                            hbuf, N, 1);   // h1 -> hbuf fp16 (ELU fused)

    // ---------- Layer 1: Fin=256, H=8, C=32 (fp16 A, 2-pass f16, fused logits) ----------
    mfma_gemm_f16_k<128, 2, 2, __half, 1><<<dim3(2, mb), 256, 0, stream>>>(
        hbuf, w1h, w1l, xh, N, 256, 256, a1s, a1d, alS, alD);
    node_aggr8_k<<<nb_nw, 256, 0, stream>>>(rowptr, csr_src, alS, alD, xh, b1,
                                            hbuf, N, 1);   // h2 -> hbuf fp16 (ELU fused)

    // ---------- Layer 2: Fin=256, H=1, C=40 (fp16 A, fused logits, fp16 x2) ----------
    mfma_gemm_f16_k<64, 4, 1, __half, 2><<<dim3(1, mb), 256, 0, stream>>>(
        hbuf, w2h, w2l, x2h, N, 256, 40, a2s, a2d, alS, alD);
    node_aggr1_k<<<nb_nw, 256, 0, stream>>>(rowptr, csr_src, alS, alD, x2h, b2,
                                            out, N);       // bias fused, direct to out
}

// Round 5
// 665.342 us; speedup vs baseline: 1.0621x; 1.0621x over previous
//
#include <hip/hip_runtime.h>
#include <hip/hip_bf16.h>
#include <hip/hip_fp16.h>
#include <math.h>

typedef __attribute__((ext_vector_type(8))) short short8;
typedef __attribute__((ext_vector_type(8))) _Float16 half8;
typedef __attribute__((ext_vector_type(4))) float f32x4;
typedef unsigned short ushort_t;
typedef unsigned long long u64_t;
struct __align__(8) us4 { ushort_t x, y, z, w; };

// round-to-nearest-even fp32 -> bf16
__device__ __forceinline__ ushort_t f2bf(float f) {
    unsigned u = __float_as_uint(f);
    u += 0x7FFFu + ((u >> 16) & 1u);
    return (ushort_t)(u >> 16);
}
__device__ __forceinline__ float bf2f(ushort_t h) {
    return __uint_as_float(((unsigned)h) << 16);
}

__device__ __forceinline__ void store_out(float* p, float v) { *p = v; }
__device__ __forceinline__ void store_out(__half* p, float v) { *p = __float2half(v); }

// ---- detect int64 edge_index + zero bucket counters (R3: was a 1-thread
// kernel doing 512 serial LLC loads ~15us; now 1 wave + folds the gtot
// memset dispatch) ----
__global__ void detect64_k(const int* __restrict__ ei, int n_check,
                           int* __restrict__ flag, int* __restrict__ gtot) {
    int t = threadIdx.x;
    gtot[t] = 0; gtot[t + 256] = 0;
    if (t < 64) {
        int zeros = 0;
        for (int i = t; i < n_check; i += 64) zeros += (ei[2 * i + 1] == 0) ? 1 : 0;
        #pragma unroll
        for (int off = 1; off < 64; off <<= 1) zeros += __shfl_xor(zeros, off);
        if (t == 0) *flag = (zeros >= n_check - 2) ? 1 : 0;
    }
}

__device__ __forceinline__ void edge_sd(const int* __restrict__ ei, int e, int E,
                                        int is64, int N, int& s_, int& d_) {
    if (e >= E) { s_ = d_ = e - E; return; }   // self-loops appended
    int s, d;
    if (is64) { s = ei[2 * e]; d = ei[2 * (E + e)]; }
    else      { s = ei[e];     d = ei[E + e]; }
    s_ = ((unsigned)s < (unsigned)N) ? s : 0;
    d_ = ((unsigned)d < (unsigned)N) ? d : 0;
}

// ================= CSR construction (2-level counting sort) =================
// Bucket = dst >> 8 (256 nodes/bucket). B = ceil(N/256) <= 512 (N <= 131072).

__global__ __launch_bounds__(256) void csr_hist_k(
    const int* __restrict__ ei, const int* __restrict__ flag,
    int* __restrict__ gtot, int E, int Etot, int N) {
    __shared__ int hc[512];
    int t = threadIdx.x;
    hc[t] = 0; hc[t + 256] = 0;
    __syncthreads();
    int base = blockIdx.x * 4096;
    int is64 = *flag;
    for (int k = 0; k < 16; ++k) {
        int e = base + k * 256 + t;
        if (e < Etot) {
            int s_, d_;
            edge_sd(ei, e, E, is64, N, s_, d_);
            atomicAdd(&hc[d_ >> 8], 1);
        }
    }
    __syncthreads();
    if (hc[t])       atomicAdd(&gtot[t], hc[t]);
    if (hc[t + 256]) atomicAdd(&gtot[t + 256], hc[t + 256]);
}

__global__ void csr_scanb_k(const int* __restrict__ gtot, int* __restrict__ boff,
                            int* __restrict__ gcur, int B) {
    __shared__ int tmp[512];
    int t = threadIdx.x;
    int v = (t < B) ? gtot[t] : 0;
    tmp[t] = v;
    __syncthreads();
    for (int off = 1; off < 512; off <<= 1) {
        int x = (t >= off) ? tmp[t - off] : 0;
        __syncthreads();
        tmp[t] += x;
        __syncthreads();
    }
    if (t < B) {
        int excl = tmp[t] - v;
        boff[t] = excl;
        gcur[t] = excl;
    }
    if (t == B - 1) boff[B] = tmp[t];
}

__global__ __launch_bounds__(256) void csr_stage_k(
    const int* __restrict__ ei, const int* __restrict__ flag,
    int* __restrict__ gcur, u64_t* __restrict__ staging,
    int E, int Etot, int N) {
    __shared__ int bcnt[512];
    __shared__ int resv[512];
    int t = threadIdx.x;
    bcnt[t] = 0; bcnt[t + 256] = 0;
    __syncthreads();
    int base = blockIdx.x * 4096;
    int is64 = *flag;
    u64_t pk[16];
    #pragma unroll
    for (int k = 0; k < 16; ++k) {
        int e = base + k * 256 + t;
        pk[k] = ~0ull;
        if (e < Etot) {
            int s_, d_;
            edge_sd(ei, e, E, is64, N, s_, d_);
            pk[k] = ((u64_t)(unsigned)d_ << 32) | (unsigned)s_;
            atomicAdd(&bcnt[d_ >> 8], 1);
        }
    }
    __syncthreads();
    {
        int c0 = bcnt[t];
        resv[t] = c0 ? atomicAdd(&gcur[t], c0) : 0;
        int c1 = bcnt[t + 256];
        resv[t + 256] = c1 ? atomicAdd(&gcur[t + 256], c1) : 0;
    }
    __syncthreads();
    bcnt[t] = 0; bcnt[t + 256] = 0;   // reuse as within-block rank cursors
    __syncthreads();
    #pragma unroll
    for (int k = 0; k < 16; ++k) {
        if (pk[k] != ~0ull) {
            int b = (int)(pk[k] >> 40);            // dst >> 8
            int pos = resv[b] + atomicAdd(&bcnt[b], 1);
            staging[pos] = pk[k];
        }
    }
}

__global__ __launch_bounds__(256) void csr_fine_k(
    const u64_t* __restrict__ staging, const int* __restrict__ boff,
    int* __restrict__ rowptr, int* __restrict__ csr_src, int N, int Etot) {
    __shared__ int hcnt[256];
    __shared__ int scn[256];
    const int b = blockIdx.x, t = threadIdx.x;
    const int lo = b << 8;
    const int base = boff[b], cnt = boff[b + 1] - base;
    hcnt[t] = 0;
    __syncthreads();
    for (int i = t; i < cnt; i += 256) {
        int dst = (int)(staging[base + i] >> 32);
        atomicAdd(&hcnt[dst - lo], 1);
    }
    __syncthreads();
    int v = hcnt[t];
    scn[t] = v;
    __syncthreads();
    for (int off = 1; off < 256; off <<= 1) {
        int x = (t >= off) ? scn[t - off] : 0;
        __syncthreads();
        scn[t] += x;
        __syncthreads();
    }
    int excl = scn[t] - v;
    if (lo + t < N) rowptr[lo + t] = base + excl;
    hcnt[t] = base + excl;   // reuse as cursor
    __syncthreads();
    for (int i = t; i < cnt; i += 256) {
        u64_t pd = staging[base + i];
        int dst = (int)(pd >> 32);
        int pos = atomicAdd(&hcnt[dst - lo], 1);
        csr_src[pos] = (int)(pd & 0xFFFFFFFFu);
    }
    if (b == 0 && t == 0) rowptr[N] = Etot;
}

// ===== weight pre-split (transposed [n][k], zero-padded to Mp rows) =====
__global__ void splitw_bf16_k(const float* __restrict__ W, ushort_t* __restrict__ Wh,
                              ushort_t* __restrict__ Wl, int K, int M, int Mp) {
    int i = blockIdx.x * 256 + threadIdx.x;
    if (i >= Mp * K) return;
    int n = i / K, k = i - n * K;
    float v = (n < M) ? W[(size_t)k * M + n] : 0.f;
    ushort_t h = f2bf(v);
    Wh[i] = h;
    Wl[i] = f2bf(v - bf2f(h));
}

__global__ void splitw_f16_k(const float* __restrict__ W, ushort_t* __restrict__ Wh,
                             ushort_t* __restrict__ Wl, int K, int M, int Mp) {
    int i = blockIdx.x * 256 + threadIdx.x;
    if (i >= Mp * K) return;
    int n = i / K, k = i - n * K;
    float v = (n < M) ? W[(size_t)k * M + n] : 0.f;
    __half h = __float2half(v);
    Wh[i] = __half_as_ushort(h);
    Wl[i] = __half_as_ushort(__float2half(v - __half2float(h)));
}

// ===== R3: pre-split fp32 A (feat) into bf16 hi/lo, row-major [N][K] =====
// Moves the fp32->bf16x2 split (8 VALU/elem, ~2048 cyc/wave inside the L0
// GEMM K-loop, run 2x via grid.x=2) into a single streaming pass.
__global__ __launch_bounds__(256) void splitA_k(const float* __restrict__ A,
                                                ushort_t* __restrict__ Hh,
                                                ushort_t* __restrict__ Hl,
                                                long total4) {
    long i = ((long)blockIdx.x * 256 + threadIdx.x) * 4;
    if (i >= total4) return;
    float4 v = *(const float4*)&A[i];
    us4 h, l;
    h.x = f2bf(v.x); l.x = f2bf(v.x - bf2f(h.x));
    h.y = f2bf(v.y); l.y = f2bf(v.y - bf2f(h.y));
    h.z = f2bf(v.z); l.z = f2bf(v.z - bf2f(h.z));
    h.w = f2bf(v.w); l.w = f2bf(v.w - bf2f(h.w));
    *(us4*)&Hh[i] = h;
    *(us4*)&Hl[i] = l;
}

// ========== split-bf16 MFMA GEMM (pre-split A hi/lo; layer 0) ==========
// A: Ahg/Alg row-major [N][K] bf16 bits. B pre-split/transposed [Mp][K].
template <int BN, int WMCNT, int WNCNT, typename TOUT, int LMODE>
__global__ __launch_bounds__(256) void mfma_gemm_k(const ushort_t* __restrict__ Ahg,
                                                   const ushort_t* __restrict__ Alg,
                                                   const ushort_t* __restrict__ BhT,
                                                   const ushort_t* __restrict__ BlT,
                                                   TOUT* __restrict__ C,
                                                   int N, int K, int M,
                                                   const float* __restrict__ a_s,
                                                   const float* __restrict__ a_d,
                                                   float* __restrict__ alS,
                                                   float* __restrict__ alD) {
    constexpr int BM = 128;
    constexpr int PAD = 40;
    constexpr int WMX = BM / WMCNT;
    constexpr int WNX = BN / WNCNT;
    constexpr int FM = WMX / 16, FN = WNX / 16;
    static_assert(FN == 4, "logit epilogue assumes WNX==64");

    __shared__ ushort_t Ah[BM * PAD], Al[BM * PAD];
    __shared__ ushort_t Bh[BN * PAD], Bl[BN * PAD];

    const int tx = threadIdx.x;
    const int wave = tx >> 6, lane = tx & 63;
    const int quad = lane >> 4, l16 = lane & 15;
    const int br = blockIdx.y * BM, bc = blockIdx.x * BN;
    const int wm = (wave / WNCNT) * WMX;
    const int wn = (wave % WNCNT) * WNX;

    f32x4 acc[FM][FN] = {};

    for (int k0 = 0; k0 < K; k0 += 32) {
        // A staging: pure 16B copies from pre-split hi/lo
        #pragma unroll
        for (int r = 0; r < 2; ++r) {
            int i = r * 256 + tx;
            int m = i >> 2, k8 = (i & 3) * 8;
            int gr = br + m;
            short8 vh = {}, vl = {};
            if (gr < N) {
                vh = *(const short8*)&Ahg[(size_t)gr * K + k0 + k8];
                vl = *(const short8*)&Alg[(size_t)gr * K + k0 + k8];
            }
            *(short8*)&Ah[m * PAD + k8] = vh;
            *(short8*)&Al[m * PAD + k8] = vl;
        }
        // B staging: pure 16B copies from pre-split transposed weights
        #pragma unroll
        for (int r = 0; r < BN / 64; ++r) {
            int i = r * 256 + tx;
            int n = i >> 2, k8 = (i & 3) * 8;
            *(short8*)&Bh[n * PAD + k8] = *(const short8*)&BhT[(size_t)(bc + n) * K + k0 + k8];
            *(short8*)&Bl[n * PAD + k8] = *(const short8*)&BlT[(size_t)(bc + n) * K + k0 + k8];
        }
        __syncthreads();

        short8 afh[FM], afl[FM];
        #pragma unroll
        for (int mi = 0; mi < FM; ++mi) {
            int row = wm + mi * 16 + l16;
            afh[mi] = *(const short8*)&Ah[row * PAD + quad * 8];
            afl[mi] = *(const short8*)&Al[row * PAD + quad * 8];
        }
        #pragma unroll
        for (int ni = 0; ni < FN; ++ni) {
            int row = wn + ni * 16 + l16;
            short8 bfh = *(const short8*)&Bh[row * PAD + quad * 8];
            short8 bfl = *(const short8*)&Bl[row * PAD + quad * 8];
            #pragma unroll
            for (int mi = 0; mi < FM; ++mi) {
                acc[mi][ni] = __builtin_amdgcn_mfma_f32_16x16x32_bf16(afh[mi], bfh, acc[mi][ni], 0, 0, 0);
                acc[mi][ni] = __builtin_amdgcn_mfma_f32_16x16x32_bf16(afh[mi], bfl, acc[mi][ni], 0, 0, 0);
                acc[mi][ni] = __builtin_amdgcn_mfma_f32_16x16x32_bf16(afl[mi], bfh, acc[mi][ni], 0, 0, 0);
            }
        }
        __syncthreads();
    }

    #pragma unroll
    for (int mi = 0; mi < FM; ++mi) {
        #pragma unroll
        for (int ni = 0; ni < FN; ++ni) {
            int gc = bc + wn + ni * 16 + l16;
            if (gc >= M) continue;
            #pragma unroll
            for (int r = 0; r < 4; ++r) {
                int gr = br + wm + mi * 16 + quad * 4 + r;
                if (gr < N) store_out(&C[(size_t)gr * M + gc], acc[mi][ni][r]);
            }
        }
    }

    // ---- fused logits ----
    float aSv[FN], aDv[FN];
    #pragma unroll
    for (int ni = 0; ni < FN; ++ni) {
        int gc = bc + wn + ni * 16 + l16;
        bool ok = gc < M;
        aSv[ni] = ok ? a_s[gc] : 0.f;
        aDv[ni] = ok ? a_d[gc] : 0.f;
    }
    if (LMODE == 1) {
        #pragma unroll
        for (int mi = 0; mi < FM; ++mi) {
            #pragma unroll
            for (int r = 0; r < 4; ++r) {
                float p1a = acc[mi][0][r] * aSv[0] + acc[mi][1][r] * aSv[1];
                float p1b = acc[mi][2][r] * aSv[2] + acc[mi][3][r] * aSv[3];
                float p2a = acc[mi][0][r] * aDv[0] + acc[mi][1][r] * aDv[1];
                float p2b = acc[mi][2][r] * aDv[2] + acc[mi][3][r] * aDv[3];
                #pragma unroll
                for (int off = 1; off < 16; off <<= 1) {
                    p1a += __shfl_xor(p1a, off);
                    p1b += __shfl_xor(p1b, off);
                    p2a += __shfl_xor(p2a, off);
                    p2b += __shfl_xor(p2b, off);
                }
                if (l16 == 0) {
                    int gr = br + wm + mi * 16 + quad * 4 + r;
                    if (gr < N) {
                        int hb = (bc + wn) >> 5;
                        alS[gr * 8 + hb]     = p1a;
                        alS[gr * 8 + hb + 1] = p1b;
                        alD[gr * 8 + hb]     = p2a;
                        alD[gr * 8 + hb + 1] = p2b;
                    }
                }
            }
        }
    } else {
        #pragma unroll
        for (int mi = 0; mi < FM; ++mi) {
            #pragma unroll
            for (int r = 0; r < 4; ++r) {
                float p1 = acc[mi][0][r] * aSv[0] + acc[mi][1][r] * aSv[1]
                         + acc[mi][2][r] * aSv[2] + acc[mi][3][r] * aSv[3];
                float p2 = acc[mi][0][r] * aDv[0] + acc[mi][1][r] * aDv[1]
                         + acc[mi][2][r] * aDv[2] + acc[mi][3][r] * aDv[3];
                #pragma unroll
                for (int off = 1; off < 16; off <<= 1) {
                    p1 += __shfl_xor(p1, off);
                    p2 += __shfl_xor(p2, off);
                }
                if (l16 == 0) {
                    int gr = br + wm + mi * 16 + quad * 4 + r;
                    if (gr < N) { alS[gr] = p1; alD[gr] = p2; }
                }
            }
        }
    }
}

// ======== fp16-A 2-pass MFMA GEMM (layers 1/2): A fp16, B pre-split fp16 hi/lo ========
template <int BN, int WMCNT, int WNCNT, typename TOUT, int LMODE>
__global__ __launch_bounds__(256) void mfma_gemm_f16_k(const __half* __restrict__ A,
                                                       const ushort_t* __restrict__ BhT,
                                                       const ushort_t* __restrict__ BlT,
                                                       TOUT* __restrict__ C,
                                                       int N, int K, int M,
                                                       const float* __restrict__ a_s,
                                                       const float* __restrict__ a_d,
                                                       float* __restrict__ alS,
                                                       float* __restrict__ alD) {
    constexpr int BM = 128;
    constexpr int PAD = 40;
    constexpr int WMX = BM / WMCNT;
    constexpr int WNX = BN / WNCNT;
    constexpr int FM = WMX / 16, FN = WNX / 16;
    static_assert(FN == 4, "logit epilogue assumes WNX==64");

    __shared__ ushort_t Ah[BM * PAD];
    __shared__ ushort_t Bh[BN * PAD], Bl[BN * PAD];

    const int tx = threadIdx.x;
    const int wave = tx >> 6, lane = tx & 63;
    const int quad = lane >> 4, l16 = lane & 15;
    const int br = blockIdx.y * BM, bc = blockIdx.x * BN;
    const int wm = (wave / WNCNT) * WMX;
    const int wn = (wave % WNCNT) * WNX;

    f32x4 acc[FM][FN] = {};

    for (int k0 = 0; k0 < K; k0 += 32) {
        #pragma unroll
        for (int r = 0; r < 2; ++r) {
            int i = r * 256 + tx;
            int m = i >> 2, k8 = (i & 3) * 8;
            int gr = br + m;
            short8 v = {};
            if (gr < N) v = *(const short8*)&A[(size_t)gr * K + k0 + k8];
            *(short8*)&Ah[m * PAD + k8] = v;
        }
        #pragma unroll
        for (int r = 0; r < BN / 64; ++r) {
            int i = r * 256 + tx;
            int n = i >> 2, k8 = (i & 3) * 8;
            *(short8*)&Bh[n * PAD + k8] = *(const short8*)&BhT[(size_t)(bc + n) * K + k0 + k8];
            *(short8*)&Bl[n * PAD + k8] = *(const short8*)&BlT[(size_t)(bc + n) * K + k0 + k8];
        }
        __syncthreads();

        half8 af[FM];
        #pragma unroll
        for (int mi = 0; mi < FM; ++mi) {
            int row = wm + mi * 16 + l16;
            af[mi] = *(const half8*)&Ah[row * PAD + quad * 8];
        }
        #pragma unroll
        for (int ni = 0; ni < FN; ++ni) {
            int row = wn + ni * 16 + l16;
            half8 bfh = *(const half8*)&Bh[row * PAD + quad * 8];
            half8 bfl = *(const half8*)&Bl[row * PAD + quad * 8];
            #pragma unroll
            for (int mi = 0; mi < FM; ++mi) {
                acc[mi][ni] = __builtin_amdgcn_mfma_f32_16x16x32_f16(af[mi], bfh, acc[mi][ni], 0, 0, 0);
                acc[mi][ni] = __builtin_amdgcn_mfma_f32_16x16x32_f16(af[mi], bfl, acc[mi][ni], 0, 0, 0);
            }
        }
        __syncthreads();
    }

    #pragma unroll
    for (int mi = 0; mi < FM; ++mi) {
        #pragma unroll
        for (int ni = 0; ni < FN; ++ni) {
            int gc = bc + wn + ni * 16 + l16;
            if (gc >= M) continue;
            #pragma unroll
            for (int r = 0; r < 4; ++r) {
                int gr = br + wm + mi * 16 + quad * 4 + r;
                if (gr < N) store_out(&C[(size_t)gr * M + gc], acc[mi][ni][r]);
            }
        }
    }

    // ---- fused logits ----
    float aSv[FN], aDv[FN];
    #pragma unroll
    for (int ni = 0; ni < FN; ++ni) {
        int gc = bc + wn + ni * 16 + l16;
        bool ok = gc < M;
        aSv[ni] = ok ? a_s[gc] : 0.f;
        aDv[ni] = ok ? a_d[gc] : 0.f;
    }
    if (LMODE == 1) {
        #pragma unroll
        for (int mi = 0; mi < FM; ++mi) {
            #pragma unroll
            for (int r = 0; r < 4; ++r) {
                float p1a = acc[mi][0][r] * aSv[0] + acc[mi][1][r] * aSv[1];
                float p1b = acc[mi][2][r] * aSv[2] + acc[mi][3][r] * aSv[3];
                float p2a = acc[mi][0][r] * aDv[0] + acc[mi][1][r] * aDv[1];
                float p2b = acc[mi][2][r] * aDv[2] + acc[mi][3][r] * aDv[3];
                #pragma unroll
                for (int off = 1; off < 16; off <<= 1) {
                    p1a += __shfl_xor(p1a, off);
                    p1b += __shfl_xor(p1b, off);
                    p2a += __shfl_xor(p2a, off);
                    p2b += __shfl_xor(p2b, off);
                }
                if (l16 == 0) {
                    int gr = br + wm + mi * 16 + quad * 4 + r;
                    if (gr < N) {
                        int hb = (bc + wn) >> 5;
                        alS[gr * 8 + hb]     = p1a;
                        alS[gr * 8 + hb + 1] = p1b;
                        alD[gr * 8 + hb]     = p2a;
                        alD[gr * 8 + hb + 1] = p2b;
                    }
                }
            }
        }
    } else {
        #pragma unroll
        for (int mi = 0; mi < FM; ++mi) {
            #pragma unroll
            for (int r = 0; r < 4; ++r) {
                float p1 = acc[mi][0][r] * aSv[0] + acc[mi][1][r] * aSv[1]
                         + acc[mi][2][r] * aSv[2] + acc[mi][3][r] * aSv[3];
                float p2 = acc[mi][0][r] * aDv[0] + acc[mi][1][r] * aDv[1]
                         + acc[mi][2][r] * aDv[2] + acc[mi][3][r] * aDv[3];
                #pragma unroll
                for (int off = 1; off < 16; off <<= 1) {
                    p1 += __shfl_xor(p1, off);
                    p2 += __shfl_xor(p2, off);
                }
                if (l16 == 0) {
                    int gr = br + wm + mi * 16 + quad * 4 + r;
                    if (gr < N) { alS[gr] = p1; alD[gr] = p2; }
                }
            }
        }
    }
}

// ================= fused per-node softmax + aggregation =================
// H=8, C=32. One wave per node. R3: depth-4 pipeline restored (R2's depth-8
// halved occupancy and kept chip-wide outstanding misses ~constant — the
// kernel is pinned at the per-CU MSHR x LLC-latency ceiling ~3.9 TB/s).
__global__ __launch_bounds__(256) void node_aggr8_k(
    const int* __restrict__ rowptr, const int* __restrict__ csr_src,
    const float* __restrict__ alS, const float* __restrict__ alD,
    const __half* __restrict__ xh, const float* __restrict__ bias,
    __half* __restrict__ out, int N, int do_elu) {
    __shared__ int    lsrc[4][64];
    __shared__ __half lalpha[4][64 * 8];
    const int wv = threadIdx.x >> 6;
    int wid = (blockIdx.x * 256 + threadIdx.x) >> 6;
    int lane = threadIdx.x & 63;
    if (wid >= N) return;
    const int d = wid;
    const int beg = rowptr[d], end = rowptr[d + 1];
    const int deg = end - beg;
    const int dcap = deg < 64 ? deg : 64;

    const int h = lane & 7, esub = lane >> 3;
    const float aDh = alD[d * 8 + h];

    const int nch = (deg + 7) >> 3;

    // sweep 1: exp sums; exp values stay in registers (static-indexed unroll)
    float exv[8] = {};
    float s = 0.f;
    #pragma unroll
    for (int c = 0; c < 8; ++c) {
        int sl = c * 8 + esub;
        int e = beg + sl;
        if (e < end) {
            int src = csr_src[e];
            float ev = alS[src * 8 + h] + aDh;
            ev = ev > 0.f ? ev : 0.2f * ev;
            float ex = __expf(fminf(ev, 30.f));
            if (h == 0) lsrc[wv][sl] = src;
            exv[c] = ex;
            s += ex;
        }
    }
    for (int c = 8; c < nch; ++c) {      // overflow (deg>64): sum only
        int e = beg + c * 8 + esub;
        if (e < end) {
            int src = csr_src[e];
            float ev = alS[src * 8 + h] + aDh;
            ev = ev > 0.f ? ev : 0.2f * ev;
            s += __expf(fminf(ev, 30.f));
        }
    }
    #pragma unroll
    for (int off = 8; off < 64; off <<= 1) s += __shfl_xor(s, off);

    // pre-scaled fp16 alpha into LDS (lane's own head h, so 1/s is local)
    float rsl = 1.f / s;
    #pragma unroll
    for (int c = 0; c < 8; ++c) {
        int sl = c * 8 + esub;
        if (sl < dcap) lalpha[wv][sl * 8 + h] = __float2half(exv[c] * rsl);
    }

    const int g = lane & 31;              // channel group: channels g*8..g*8+7
    const int hh = g >> 2;                // head of this channel group
    const int p = lane >> 5;              // edge parity
    const float rs = __shfl(rsl, hh);     // only needed by the overflow path

    const char* xb = (const char*)xh;
    const unsigned goff = (unsigned)(g << 4);   // byte offset within a 512B row

    const int T = (dcap + 1) >> 1;        // pair-steps over cached edges (T>=1)
    __half2 a2q[4];
    float4 rq[4];
    __half2 hacc[4] = {};

    // prologue: stages 0..3 (clamped addresses are always valid; alpha zeroed)
    #pragma unroll
    for (int i = 0; i < 4; ++i) {
        int e0 = 2 * i + p;
        int idx = e0 < dcap ? e0 : dcap - 1;
        int sv = lsrc[wv][idx];
        ushort_t ub = __half_as_ushort(lalpha[wv][idx * 8 + hh]);
        if (e0 >= dcap) ub = 0;
        a2q[i] = __half2half2(__ushort_as_half(ub));
        rq[i] = *(const float4*)(xb + (((unsigned)sv << 9) + goff));
    }

    #define PROC8(i)                                                        \
    {                                                                       \
        float4 raw = rq[i];                                                 \
        __half2 a2 = a2q[i];                                                \
        int e0 = 2 * (t + 4 + (i)) + p;                                     \
        ushort_t ub = 0;                                                    \
        if (e0 < dcap) {                                                    \
            int srcn = lsrc[wv][e0];                                        \
            ub = __half_as_ushort(lalpha[wv][e0 * 8 + hh]);                 \
            rq[i] = *(const float4*)(xb + (((unsigned)srcn << 9) + goff));  \
        }                                                                   \
        a2q[i] = __half2half2(__ushort_as_half(ub));                        \
        const __half2* hp = (const __half2*)&raw;                           \
        hacc[0] = __hfma2(hp[0], a2, hacc[0]);                              \
        hacc[1] = __hfma2(hp[1], a2, hacc[1]);                              \
        hacc[2] = __hfma2(hp[2], a2, hacc[2]);                              \
        hacc[3] = __hfma2(hp[3], a2, hacc[3]);                              \
    }
    #define TAIL8(i)                                                        \
    {                                                                       \
        float4 raw = rq[i];                                                 \
        __half2 a2 = a2q[i];                                                \
        const __half2* hp = (const __half2*)&raw;                           \
        hacc[0] = __hfma2(hp[0], a2, hacc[0]);                              \
        hacc[1] = __hfma2(hp[1], a2, hacc[1]);                              \
        hacc[2] = __hfma2(hp[2], a2, hacc[2]);                              \
        hacc[3] = __hfma2(hp[3], a2, hacc[3]);                              \
    }
    int t = 0;
    for (; t + 4 <= T; t += 4) { PROC8(0) PROC8(1) PROC8(2) PROC8(3) }
    {
        int rem = T - t;   // 0..3, wave-uniform
        if (rem > 0) { TAIL8(0) if (rem > 1) { TAIL8(1) if (rem > 2) TAIL8(2) } }
    }
    #undef PROC8
    #undef TAIL8

    // overflow gather (deg>64): recompute path, 2 edges/step via shuffles
    for (int c = 8; c < nch; ++c) {
        int base = beg + c * 8;
        int e = base + esub;
        int src_l = 0; float ex_l = 0.f;
        if (e < end) {
            src_l = csr_src[e];
            float ev = alS[src_l * 8 + h] + aDh;
            ev = ev > 0.f ? ev : 0.2f * ev;
            ex_l = __expf(fminf(ev, 30.f));
        }
        int cnt = end - base; if (cnt > 8) cnt = 8;
        int steps = (cnt + 1) >> 1;
        for (int t2 = 0; t2 < steps; ++t2) {
            int j = t2 * 2 + p;
            int jc = j < cnt ? j : (cnt - 1);
            int src = __shfl(src_l, jc * 8);
            float af = __shfl(ex_l, jc * 8 + hh) * rs;
            if (j >= cnt) af = 0.f;
            __half2 a2 = __float2half2_rn(af);
            const float4 raw = *(const float4*)(xb + (((unsigned)src << 9) + goff));
            const __half2* hp = (const __half2*)&raw;
            hacc[0] = __hfma2(hp[0], a2, hacc[0]);
            hacc[1] = __hfma2(hp[1], a2, hacc[1]);
            hacc[2] = __hfma2(hp[2], a2, hacc[2]);
            hacc[3] = __hfma2(hp[3], a2, hacc[3]);
        }
    }

    // merge parity halves (lane ^ 32)
    #pragma unroll
    for (int k = 0; k < 4; ++k) {
        int vi = __shfl_xor(*(int*)&hacc[k], 32);
        hacc[k] = __hadd2(hacc[k], *(__half2*)&vi);
    }

    if (p == 0) {
        float2 f0 = __half22float2(hacc[0]);
        float2 f1 = __half22float2(hacc[1]);
        float2 f2 = __half22float2(hacc[2]);
        float2 f3 = __half22float2(hacc[3]);
        const float4 bv0 = *(const float4*)&bias[g * 8];
        const float4 bv1 = *(const float4*)&bias[g * 8 + 4];
        float o[8];
        o[0] = f0.x + bv0.x; o[1] = f0.y + bv0.y;
        o[2] = f1.x + bv0.z; o[3] = f1.y + bv0.w;
        o[4] = f2.x + bv1.x; o[5] = f2.y + bv1.y;
        o[6] = f3.x + bv1.z; o[7] = f3.y + bv1.w;
        if (do_elu) {
            #pragma unroll
            for (int k = 0; k < 8; ++k) o[k] = o[k] > 0.f ? o[k] : (__expf(o[k]) - 1.f);
        }
        float4 st;
        ((__half2*)&st)[0] = __floats2half2_rn(o[0], o[1]);
        ((__half2*)&st)[1] = __floats2half2_rn(o[2], o[3]);
        ((__half2*)&st)[2] = __floats2half2_rn(o[4], o[5]);
        ((__half2*)&st)[3] = __floats2half2_rn(o[6], o[7]);
        *(float4*)(out + ((size_t)d << 8) + g * 8) = st;
    }
}

// H=1, C=40. One wave per node. R3: depth-4 restored.
__global__ __launch_bounds__(256) void node_aggr1_k(
    const int* __restrict__ rowptr, const int* __restrict__ csr_src,
    const float* __restrict__ alS, const float* __restrict__ alD,
    const __half* __restrict__ xh2, const float* __restrict__ bias,
    float* __restrict__ out, int N) {
    __shared__ int   lsrc1[4][64];
    __shared__ float lal1[4][64];
    const int wv = threadIdx.x >> 6;
    int wid = (blockIdx.x * 256 + threadIdx.x) >> 6;
    int lane = threadIdx.x & 63;
    if (wid >= N) return;
    const int d = wid;
    const int beg = rowptr[d], end = rowptr[d + 1];
    const int deg = end - beg;
    const int dcap = deg < 64 ? deg : 64;
    const float aD = alD[d];

    float ex0 = 0.f;
    {
        int e = beg + lane;
        if (e < end) {
            int src0 = csr_src[e];
            float ev = alS[src0] + aD;
            ev = ev > 0.f ? ev : 0.2f * ev;
            ex0 = __expf(fminf(ev, 30.f));
            lsrc1[wv][lane] = src0;
        }
    }
    float s = ex0;
    for (int e = beg + 64 + lane; e < end; e += 64) {
        int src = csr_src[e];
        float ev = alS[src] + aD;
        ev = ev > 0.f ? ev : 0.2f * ev;
        s += __expf(fminf(ev, 30.f));
    }
    #pragma unroll
    for (int off = 1; off < 64; off <<= 1) s += __shfl_xor(s, off);
    const float rs = 1.f / s;
    if (lane < dcap) lal1[wv][lane] = ex0 * rs;

    const int q = lane & 31;              // channel pair: channels q*2, q*2+1
    const int p = lane >> 5;              // edge parity
    const int qg = q < 20 ? q : 19;       // clamp idle lanes inside the 80B row
    const unsigned qb = (unsigned)(qg << 2);
    const char* xb2 = (const char*)xh2;

    const int T = (dcap + 1) >> 1;
    float alq[4];
    __half2 rq1[4];
    float ax = 0.f, ay = 0.f;

    #pragma unroll
    for (int i = 0; i < 4; ++i) {
        int e0 = 2 * i + p;
        int idx = e0 < dcap ? e0 : dcap - 1;
        int sv = lsrc1[wv][idx];
        float av = lal1[wv][idx];
        alq[i] = e0 < dcap ? av : 0.f;
        rq1[i] = *(const __half2*)(xb2 + ((unsigned)sv * 80u + qb));
    }

    #define PROC1(i)                                                        \
    {                                                                       \
        float2 rf = __half22float2(rq1[i]);                                 \
        float al = alq[i];                                                  \
        int e0 = 2 * (t + 4 + (i)) + p;                                     \
        float an = 0.f;                                                     \
        if (e0 < dcap) {                                                    \
            int sv = lsrc1[wv][e0];                                         \
            an = lal1[wv][e0];                                              \
            rq1[i] = *(const __half2*)(xb2 + ((unsigned)sv * 80u + qb));    \
        }                                                                   \
        alq[i] = an;                                                        \
        ax += rf.x * al; ay += rf.y * al;                                   \
    }
    #define TAIL1(i)                                                        \
    {                                                                       \
        float2 rf = __half22float2(rq1[i]);                                 \
        ax += rf.x * alq[i]; ay += rf.y * alq[i];                           \
    }
    int t = 0;
    for (; t + 4 <= T; t += 4) { PROC1(0) PROC1(1) PROC1(2) PROC1(3) }
    {
        int rem = T - t;
        if (rem > 0) { TAIL1(0) if (rem > 1) { TAIL1(1) if (rem > 2) TAIL1(2) } }
    }
    #undef PROC1
    #undef TAIL1

    // overflow (deg > 64): refill LDS per 64-edge chunk, simple paired loop
    for (int eb = beg + 64; eb < end; eb += 64) {
        int e = eb + lane;
        int cnt = end - eb; if (cnt > 64) cnt = 64;
        if (e < end) {
            int srcl = csr_src[e];
            float ev = alS[srcl] + aD;
            ev = ev > 0.f ? ev : 0.2f * ev;
            lsrc1[wv][lane] = srcl;
            lal1[wv][lane] = __expf(fminf(ev, 30.f)) * rs;
        }
        int T2 = (cnt + 1) >> 1;
        for (int t2 = 0; t2 < T2; ++t2) {
            int e0 = 2 * t2 + p;
            float al = 0.f;
            int sv = lsrc1[wv][0];
            if (e0 < cnt) { sv = lsrc1[wv][e0]; al = lal1[wv][e0]; }
            float2 rf = __half22float2(*(const __half2*)(xb2 + ((unsigned)sv * 80u + qb)));
            ax += rf.x * al; ay += rf.y * al;
        }
    }

    // merge parity halves
    ax += __shfl_xor(ax, 32);
    ay += __shfl_xor(ay, 32);

    if (p == 0 && q < 20) {
        float2 bv = *(const float2*)&bias[q * 2];
        float2 st = make_float2(ax + bv.x, ay + bv.y);
        *(float2*)&out[(size_t)d * 40 + q * 2] = st;
    }
}

extern "C" void kernel_launch(void* const* d_in, const int* in_sizes, int n_in,
                              void* d_out, int out_size, void* d_ws, size_t ws_size,
                              hipStream_t stream) {
    const float* feat = (const float*)d_in[0];
    const int*   ei   = (const int*)d_in[1];
    const float* W0   = (const float*)d_in[2];
    const float* a0s  = (const float*)d_in[3];
    const float* a0d  = (const float*)d_in[4];
    const float* b0   = (const float*)d_in[5];
    const float* W1   = (const float*)d_in[6];
    const float* a1s  = (const float*)d_in[7];
    const float* a1d  = (const float*)d_in[8];
    const float* b1   = (const float*)d_in[9];
    const float* W2   = (const float*)d_in[10];
    const float* a2s  = (const float*)d_in[11];
    const float* a2d  = (const float*)d_in[12];
    const float* b2   = (const float*)d_in[13];
    float* out = (float*)d_out;

    const int N = in_sizes[0] / 128;   // 100000
    const int E = in_sizes[1] / 2;     // 1600000
    const int Etot = E + N;

    // workspace layout (~112 MB total)
    __half* hbuf = (__half*)d_ws;                     // N*256 fp16 (aggr out / gemm A)
    __half* xh   = hbuf + (size_t)N * 256;            // N*256 fp16 (gemm out; CSR staging alias)
    __half* x2h  = xh + (size_t)N * 256;              // N*40 fp16 (layer-2 gemm out)
    float*  alS  = (float*)(x2h + (size_t)N * 40);    // N*8
    float*  alD  = alS + (size_t)N * 8;               // N*8
    int* rowptr   = (int*)(alD + (size_t)N * 8);      // N+1
    int* gtot     = rowptr + N + 1;                   // 512 (bucket counts)
    int* boff     = gtot + 512;                       // 513 (bucket offsets)
    int* gcur     = boff + 513;                       // 512 (bucket cursors)
    int* csr_src  = gcur + 512;                       // Etot
    int* flag     = csr_src + Etot;                   // 1
    // pre-split transposed weights (16B aligned)
    uintptr_t wsp = ((uintptr_t)(flag + 1) + 15) & ~(uintptr_t)15;
    ushort_t* w0h = (ushort_t*)wsp;                   // 256*128
    ushort_t* w0l = w0h + 256 * 128;
    ushort_t* w1h = w0l + 256 * 128;                  // 256*256
    ushort_t* w1l = w1h + 256 * 256;
    ushort_t* w2h = w1l + 256 * 256;                  // 64*256
    ushort_t* w2l = w2h + 64 * 256;

    // CSR staging (dead once csr_fine_k completes; aliases xh which is first
    // written by the layer-0 GEMM afterwards — stream-ordered, no hazard)
    u64_t* staging = (u64_t*)xh;                      // Etot * 8B <= 13.7MB < 51.2MB

    // pre-split A for layer 0 (dead after L0 GEMM; aliases hbuf, whose first
    // write is the L0 aggregation — stream-ordered, no hazard).
    // size: 2 * N*128 ushort = N*512B = exactly hbuf's N*256 fp16.
    ushort_t* fh = (ushort_t*)hbuf;                   // N*128 bf16-hi
    ushort_t* fl = fh + (size_t)N * 128;              // N*128 bf16-lo

    const int B     = (N + 255) >> 8;                 // buckets of 256 nodes (<=512)
    const int nb_e4 = (Etot + 4095) / 4096;           // hist/stage grid
    const int nb_nw = (N + 3) / 4;

    // ---- CSR build (counting sort) + weight/A pre-split ----
    detect64_k<<<1, 256, 0, stream>>>(ei, 512, flag, gtot);   // also zeroes gtot
    csr_hist_k<<<nb_e4, 256, 0, stream>>>(ei, flag, gtot, E, Etot, N);
    csr_scanb_k<<<1, 512, 0, stream>>>(gtot, boff, gcur, B);
    csr_stage_k<<<nb_e4, 256, 0, stream>>>(ei, flag, gcur, staging, E, Etot, N);
    csr_fine_k<<<B, 256, 0, stream>>>(staging, boff, rowptr, csr_src, N, Etot);
    splitw_bf16_k<<<128, 256, 0, stream>>>(W0, w0h, w0l, 128, 256, 256);
    splitw_f16_k<<<256, 256, 0, stream>>>(W1, w1h, w1l, 256, 256, 256);
    splitw_f16_k<<<64, 256, 0, stream>>>(W2, w2h, w2l, 256, 40, 64);
    splitA_k<<<(int)(((long)N * 128 / 4 + 255) / 256), 256, 0, stream>>>(
        feat, fh, fl, (long)N * 128);

    const int mb = (N + 127) / 128;

    // ---------- Layer 0: Fin=128, H=8, C=32 (pre-split bf16 A, 3-pass, fused logits) ----------
    mfma_gemm_k<128, 2, 2, __half, 1><<<dim3(2, mb), 256, 0, stream>>>(
        fh, fl, w0h, w0l, xh, N, 128, 256, a0s, a0d, alS, alD);
    node_aggr8_k<<<nb_nw, 256, 0, stream>>>(rowptr, csr_src, alS, alD, xh, b0,
                                            hbuf, N, 1);   // h1 -> hbuf fp16 (ELU fused)

    // ---------- Layer 1: Fin=256, H=8, C=32 (fp16 A, 2-pass f16, fused logits) ----------
    mfma_gemm_f16_k<128, 2, 2, __half, 1><<<dim3(2, mb), 256, 0, stream>>>(
        hbuf, w1h, w1l, xh, N, 256, 256, a1s, a1d, alS, alD);
    node_aggr8_k<<<nb_nw, 256, 0, stream>>>(rowptr, csr_src, alS, alD, xh, b1,
                                            hbuf, N, 1);   // h2 -> hbuf fp16 (ELU fused)

    // ---------- Layer 2: Fin=256, H=1, C=40 (fp16 A, fused logits, fp16 x2) ----------
    mfma_gemm_f16_k<64, 4, 1, __half, 2><<<dim3(1, mb), 256, 0, stream>>>(
        hbuf, w2h, w2l, x2h, N, 256, 40, a2s, a2d, alS, alD);
    node_aggr1_k<<<nb_nw, 256, 0, stream>>>(rowptr, csr_src, alS, alD, x2h, b2,
                                            out, N);       // bias fused, direct to out
}

// Round 6
// 655.764 us; speedup vs baseline: 1.0776x; 1.0146x over previous
//
#include <hip/hip_runtime.h>
#include <hip/hip_bf16.h>
#include <hip/hip_fp16.h>
#include <math.h>

typedef __attribute__((ext_vector_type(8))) short short8;
typedef __attribute__((ext_vector_type(8))) _Float16 half8;
typedef __attribute__((ext_vector_type(4))) float f32x4;
typedef unsigned short ushort_t;
typedef unsigned long long u64_t;
struct __align__(8) us4 { ushort_t x, y, z, w; };

// async global->LDS, 16B per lane (m97 pattern). LDS dest must be lane-linear.
#define GLDS16(gsrc, ldst)                                                   \
    __builtin_amdgcn_global_load_lds(                                        \
        (const __attribute__((address_space(1))) void*)(gsrc),               \
        (__attribute__((address_space(3))) void*)(ldst), 16, 0, 0)

// round-to-nearest-even fp32 -> bf16
__device__ __forceinline__ ushort_t f2bf(float f) {
    unsigned u = __float_as_uint(f);
    u += 0x7FFFu + ((u >> 16) & 1u);
    return (ushort_t)(u >> 16);
}
__device__ __forceinline__ float bf2f(ushort_t h) {
    return __uint_as_float(((unsigned)h) << 16);
}

__device__ __forceinline__ void store_out(float* p, float v) { *p = v; }
__device__ __forceinline__ void store_out(__half* p, float v) { *p = __float2half(v); }

// ---- detect int64 edge_index + zero bucket counters ----
__global__ void detect64_k(const int* __restrict__ ei, int n_check,
                           int* __restrict__ flag, int* __restrict__ gtot) {
    int t = threadIdx.x;
    gtot[t] = 0; gtot[t + 256] = 0;
    if (t < 64) {
        int zeros = 0;
        for (int i = t; i < n_check; i += 64) zeros += (ei[2 * i + 1] == 0) ? 1 : 0;
        #pragma unroll
        for (int off = 1; off < 64; off <<= 1) zeros += __shfl_xor(zeros, off);
        if (t == 0) *flag = (zeros >= n_check - 2) ? 1 : 0;
    }
}

__device__ __forceinline__ void edge_sd(const int* __restrict__ ei, int e, int E,
                                        int is64, int N, int& s_, int& d_) {
    if (e >= E) { s_ = d_ = e - E; return; }   // self-loops appended
    int s, d;
    if (is64) { s = ei[2 * e]; d = ei[2 * (E + e)]; }
    else      { s = ei[e];     d = ei[E + e]; }
    s_ = ((unsigned)s < (unsigned)N) ? s : 0;
    d_ = ((unsigned)d < (unsigned)N) ? d : 0;
}

// ================= CSR construction (2-level counting sort) =================
__global__ __launch_bounds__(256) void csr_hist_k(
    const int* __restrict__ ei, const int* __restrict__ flag,
    int* __restrict__ gtot, int E, int Etot, int N) {
    __shared__ int hc[512];
    int t = threadIdx.x;
    hc[t] = 0; hc[t + 256] = 0;
    __syncthreads();
    int base = blockIdx.x * 4096;
    int is64 = *flag;
    for (int k = 0; k < 16; ++k) {
        int e = base + k * 256 + t;
        if (e < Etot) {
            int s_, d_;
            edge_sd(ei, e, E, is64, N, s_, d_);
            atomicAdd(&hc[d_ >> 8], 1);
        }
    }
    __syncthreads();
    if (hc[t])       atomicAdd(&gtot[t], hc[t]);
    if (hc[t + 256]) atomicAdd(&gtot[t + 256], hc[t + 256]);
}

__global__ void csr_scanb_k(const int* __restrict__ gtot, int* __restrict__ boff,
                            int* __restrict__ gcur, int B) {
    __shared__ int tmp[512];
    int t = threadIdx.x;
    int v = (t < B) ? gtot[t] : 0;
    tmp[t] = v;
    __syncthreads();
    for (int off = 1; off < 512; off <<= 1) {
        int x = (t >= off) ? tmp[t - off] : 0;
        __syncthreads();
        tmp[t] += x;
        __syncthreads();
    }
    if (t < B) {
        int excl = tmp[t] - v;
        boff[t] = excl;
        gcur[t] = excl;
    }
    if (t == B - 1) boff[B] = tmp[t];
}

__global__ __launch_bounds__(256) void csr_stage_k(
    const int* __restrict__ ei, const int* __restrict__ flag,
    int* __restrict__ gcur, u64_t* __restrict__ staging,
    int E, int Etot, int N) {
    __shared__ int bcnt[512];
    __shared__ int resv[512];
    int t = threadIdx.x;
    bcnt[t] = 0; bcnt[t + 256] = 0;
    __syncthreads();
    int base = blockIdx.x * 4096;
    int is64 = *flag;
    u64_t pk[16];
    #pragma unroll
    for (int k = 0; k < 16; ++k) {
        int e = base + k * 256 + t;
        pk[k] = ~0ull;
        if (e < Etot) {
            int s_, d_;
            edge_sd(ei, e, E, is64, N, s_, d_);
            pk[k] = ((u64_t)(unsigned)d_ << 32) | (unsigned)s_;
            atomicAdd(&bcnt[d_ >> 8], 1);
        }
    }
    __syncthreads();
    {
        int c0 = bcnt[t];
        resv[t] = c0 ? atomicAdd(&gcur[t], c0) : 0;
        int c1 = bcnt[t + 256];
        resv[t + 256] = c1 ? atomicAdd(&gcur[t + 256], c1) : 0;
    }
    __syncthreads();
    bcnt[t] = 0; bcnt[t + 256] = 0;   // reuse as within-block rank cursors
    __syncthreads();
    #pragma unroll
    for (int k = 0; k < 16; ++k) {
        if (pk[k] != ~0ull) {
            int b = (int)(pk[k] >> 40);            // dst >> 8
            int pos = resv[b] + atomicAdd(&bcnt[b], 1);
            staging[pos] = pk[k];
        }
    }
}

__global__ __launch_bounds__(256) void csr_fine_k(
    const u64_t* __restrict__ staging, const int* __restrict__ boff,
    int* __restrict__ rowptr, int* __restrict__ csr_src, int N, int Etot) {
    __shared__ int hcnt[256];
    __shared__ int scn[256];
    const int b = blockIdx.x, t = threadIdx.x;
    const int lo = b << 8;
    const int base = boff[b], cnt = boff[b + 1] - base;
    hcnt[t] = 0;
    __syncthreads();
    for (int i = t; i < cnt; i += 256) {
        int dst = (int)(staging[base + i] >> 32);
        atomicAdd(&hcnt[dst - lo], 1);
    }
    __syncthreads();
    int v = hcnt[t];
    scn[t] = v;
    __syncthreads();
    for (int off = 1; off < 256; off <<= 1) {
        int x = (t >= off) ? scn[t - off] : 0;
        __syncthreads();
        scn[t] += x;
        __syncthreads();
    }
    int excl = scn[t] - v;
    if (lo + t < N) rowptr[lo + t] = base + excl;
    hcnt[t] = base + excl;   // reuse as cursor
    __syncthreads();
    for (int i = t; i < cnt; i += 256) {
        u64_t pd = staging[base + i];
        int dst = (int)(pd >> 32);
        int pos = atomicAdd(&hcnt[dst - lo], 1);
        csr_src[pos] = (int)(pd & 0xFFFFFFFFu);
    }
    if (b == 0 && t == 0) rowptr[N] = Etot;
}

// ===== R5: fused pre-split (W0 bf16 hi/lo, W1/W2 f16 hi/lo, feat bf16 hi/lo)
// One dispatch, grid-partitioned — replaces 4 stream-serialized kernels.
__global__ __launch_bounds__(256) void prep_k(
    const float* __restrict__ W0, const float* __restrict__ W1,
    const float* __restrict__ W2, const float* __restrict__ feat,
    ushort_t* __restrict__ w0h, ushort_t* __restrict__ w0l,
    ushort_t* __restrict__ w1h, ushort_t* __restrict__ w1l,
    ushort_t* __restrict__ w2h, ushort_t* __restrict__ w2l,
    ushort_t* __restrict__ fh, ushort_t* __restrict__ fl, long totalA4) {
    int b = blockIdx.x, tx = threadIdx.x;
    if (b < 128) {                       // W0: K=128, M=256, Mp=256, bf16
        int i = b * 256 + tx;
        int n = i >> 7, k = i & 127;
        float v = W0[(size_t)k * 256 + n];
        ushort_t h = f2bf(v);
        w0h[i] = h;
        w0l[i] = f2bf(v - bf2f(h));
    } else if (b < 384) {                // W1: K=256, M=256, Mp=256, f16
        int i = (b - 128) * 256 + tx;
        int n = i >> 8, k = i & 255;
        float v = W1[(size_t)k * 256 + n];
        __half h = __float2half(v);
        w1h[i] = __half_as_ushort(h);
        w1l[i] = __half_as_ushort(__float2half(v - __half2float(h)));
    } else if (b < 448) {                // W2: K=256, M=40, Mp=64, f16
        int i = (b - 384) * 256 + tx;
        int n = i >> 8, k = i & 255;
        float v = (n < 40) ? W2[(size_t)k * 40 + n] : 0.f;
        __half h = __float2half(v);
        w2h[i] = __half_as_ushort(h);
        w2l[i] = __half_as_ushort(__float2half(v - __half2float(h)));
    } else {                             // feat: bf16 hi/lo split, 4 elems/thread
        long i = ((long)(b - 448) * 256 + tx) * 4;
        if (i >= totalA4) return;
        float4 v = *(const float4*)&feat[i];
        us4 h, l;
        h.x = f2bf(v.x); l.x = f2bf(v.x - bf2f(h.x));
        h.y = f2bf(v.y); l.y = f2bf(v.y - bf2f(h.y));
        h.z = f2bf(v.z); l.z = f2bf(v.z - bf2f(h.z));
        h.w = f2bf(v.w); l.w = f2bf(v.w - bf2f(h.w));
        *(us4*)&fh[i] = h;
        *(us4*)&fl[i] = l;
    }
}

// ========== split-bf16 MFMA GEMM (pre-split A hi/lo; layer 0) ==========
// R5: m97-style staging — global_load_lds width-16 into linear [128][32] LDS
// (no PAD). 4x fewer staging instructions, no VGPR round-trip. OOB rows are
// clamped to N-1 (garbage affects only guarded rows).
template <int BN, int WMCNT, int WNCNT, typename TOUT, int LMODE>
__global__ __launch_bounds__(256) void mfma_gemm_k(const ushort_t* __restrict__ Ahg,
                                                   const ushort_t* __restrict__ Alg,
                                                   const ushort_t* __restrict__ BhT,
                                                   const ushort_t* __restrict__ BlT,
                                                   TOUT* __restrict__ C,
                                                   int N, int K, int M, int Mst,
                                                   const float* __restrict__ a_s,
                                                   const float* __restrict__ a_d,
                                                   float* __restrict__ alS,
                                                   float* __restrict__ alD) {
    constexpr int BM = 128;
    constexpr int WMX = BM / WMCNT;
    constexpr int WNX = BN / WNCNT;
    constexpr int FM = WMX / 16, FN = WNX / 16;
    static_assert(FN == 4, "logit epilogue assumes WNX==64");

    __shared__ ushort_t Ah[BM * 32], Al[BM * 32];
    __shared__ ushort_t Bh[BN * 32], Bl[BN * 32];

    const int tx = threadIdx.x;
    const int wave = tx >> 6, lane = tx & 63;
    const int quad = lane >> 4, l16 = lane & 15;
    const int br = blockIdx.y * BM, bc = blockIdx.x * BN;
    const int wm = (wave / WNCNT) * WMX;
    const int wn = (wave % WNCNT) * WNX;

    f32x4 acc[FM][FN] = {};

    for (int k0 = 0; k0 < K; k0 += 32) {
        #pragma unroll
        for (int r = 0; r < 2; ++r) {
            int i = r * 256 + tx;
            int m = i >> 2, kc = (i & 3) * 8;
            int gr = br + m; gr = gr < N ? gr : N - 1;
            size_t go = (size_t)gr * K + k0 + kc;
            GLDS16(&Ahg[go], &Ah[(size_t)i * 8]);
            GLDS16(&Alg[go], &Al[(size_t)i * 8]);
        }
        #pragma unroll
        for (int r = 0; r < BN / 64; ++r) {
            int i = r * 256 + tx;
            int n = i >> 2, kc = (i & 3) * 8;
            size_t go = (size_t)(bc + n) * K + k0 + kc;
            GLDS16(&BhT[go], &Bh[(size_t)i * 8]);
            GLDS16(&BlT[go], &Bl[(size_t)i * 8]);
        }
        __syncthreads();

        short8 afh[FM], afl[FM];
        #pragma unroll
        for (int mi = 0; mi < FM; ++mi) {
            int row = wm + mi * 16 + l16;
            afh[mi] = *(const short8*)&Ah[row * 32 + quad * 8];
            afl[mi] = *(const short8*)&Al[row * 32 + quad * 8];
        }
        #pragma unroll
        for (int ni = 0; ni < FN; ++ni) {
            int row = wn + ni * 16 + l16;
            short8 bfh = *(const short8*)&Bh[row * 32 + quad * 8];
            short8 bfl = *(const short8*)&Bl[row * 32 + quad * 8];
            #pragma unroll
            for (int mi = 0; mi < FM; ++mi) {
                acc[mi][ni] = __builtin_amdgcn_mfma_f32_16x16x32_bf16(afh[mi], bfh, acc[mi][ni], 0, 0, 0);
                acc[mi][ni] = __builtin_amdgcn_mfma_f32_16x16x32_bf16(afh[mi], bfl, acc[mi][ni], 0, 0, 0);
                acc[mi][ni] = __builtin_amdgcn_mfma_f32_16x16x32_bf16(afl[mi], bfh, acc[mi][ni], 0, 0, 0);
            }
        }
        __syncthreads();
    }

    #pragma unroll
    for (int mi = 0; mi < FM; ++mi) {
        #pragma unroll
        for (int ni = 0; ni < FN; ++ni) {
            int gc = bc + wn + ni * 16 + l16;
            #pragma unroll
            for (int r = 0; r < 4; ++r) {
                int gr = br + wm + mi * 16 + quad * 4 + r;
                if (gr < N) store_out(&C[(size_t)gr * Mst + gc], acc[mi][ni][r]);
            }
        }
    }

    // ---- fused logits ----
    float aSv[FN], aDv[FN];
    #pragma unroll
    for (int ni = 0; ni < FN; ++ni) {
        int gc = bc + wn + ni * 16 + l16;
        bool ok = gc < M;
        aSv[ni] = ok ? a_s[gc] : 0.f;
        aDv[ni] = ok ? a_d[gc] : 0.f;
    }
    if (LMODE == 1) {
        #pragma unroll
        for (int mi = 0; mi < FM; ++mi) {
            #pragma unroll
            for (int r = 0; r < 4; ++r) {
                float p1a = acc[mi][0][r] * aSv[0] + acc[mi][1][r] * aSv[1];
                float p1b = acc[mi][2][r] * aSv[2] + acc[mi][3][r] * aSv[3];
                float p2a = acc[mi][0][r] * aDv[0] + acc[mi][1][r] * aDv[1];
                float p2b = acc[mi][2][r] * aDv[2] + acc[mi][3][r] * aDv[3];
                #pragma unroll
                for (int off = 1; off < 16; off <<= 1) {
                    p1a += __shfl_xor(p1a, off);
                    p1b += __shfl_xor(p1b, off);
                    p2a += __shfl_xor(p2a, off);
                    p2b += __shfl_xor(p2b, off);
                }
                if (l16 == 0) {
                    int gr = br + wm + mi * 16 + quad * 4 + r;
                    if (gr < N) {
                        int hb = (bc + wn) >> 5;
                        alS[gr * 8 + hb]     = p1a;
                        alS[gr * 8 + hb + 1] = p1b;
                        alD[gr * 8 + hb]     = p2a;
                        alD[gr * 8 + hb + 1] = p2b;
                    }
                }
            }
        }
    } else {
        #pragma unroll
        for (int mi = 0; mi < FM; ++mi) {
            #pragma unroll
            for (int r = 0; r < 4; ++r) {
                float p1 = acc[mi][0][r] * aSv[0] + acc[mi][1][r] * aSv[1]
                         + acc[mi][2][r] * aSv[2] + acc[mi][3][r] * aSv[3];
                float p2 = acc[mi][0][r] * aDv[0] + acc[mi][1][r] * aDv[1]
                         + acc[mi][2][r] * aDv[2] + acc[mi][3][r] * aDv[3];
                #pragma unroll
                for (int off = 1; off < 16; off <<= 1) {
                    p1 += __shfl_xor(p1, off);
                    p2 += __shfl_xor(p2, off);
                }
                if (l16 == 0) {
                    int gr = br + wm + mi * 16 + quad * 4 + r;
                    if (gr < N) { alS[gr] = p1; alD[gr] = p2; }
                }
            }
        }
    }
}

// ======== fp16-A 2-pass MFMA GEMM (layers 1/2). R5: glds staging. ========
template <int BN, int WMCNT, int WNCNT, typename TOUT, int LMODE>
__global__ __launch_bounds__(256) void mfma_gemm_f16_k(const __half* __restrict__ A,
                                                       const ushort_t* __restrict__ BhT,
                                                       const ushort_t* __restrict__ BlT,
                                                       TOUT* __restrict__ C,
                                                       int N, int K, int M, int Mst,
                                                       const float* __restrict__ a_s,
                                                       const float* __restrict__ a_d,
                                                       float* __restrict__ alS,
                                                       float* __restrict__ alD) {
    constexpr int BM = 128;
    constexpr int WMX = BM / WMCNT;
    constexpr int WNX = BN / WNCNT;
    constexpr int FM = WMX / 16, FN = WNX / 16;
    static_assert(FN == 4, "logit epilogue assumes WNX==64");

    __shared__ ushort_t Ah[BM * 32];
    __shared__ ushort_t Bh[BN * 32], Bl[BN * 32];

    const int tx = threadIdx.x;
    const int wave = tx >> 6, lane = tx & 63;
    const int quad = lane >> 4, l16 = lane & 15;
    const int br = blockIdx.y * BM, bc = blockIdx.x * BN;
    const int wm = (wave / WNCNT) * WMX;
    const int wn = (wave % WNCNT) * WNX;

    f32x4 acc[FM][FN] = {};

    for (int k0 = 0; k0 < K; k0 += 32) {
        #pragma unroll
        for (int r = 0; r < 2; ++r) {
            int i = r * 256 + tx;
            int m = i >> 2, kc = (i & 3) * 8;
            int gr = br + m; gr = gr < N ? gr : N - 1;
            GLDS16(&A[(size_t)gr * K + k0 + kc], &Ah[(size_t)i * 8]);
        }
        #pragma unroll
        for (int r = 0; r < BN / 64; ++r) {
            int i = r * 256 + tx;
            int n = i >> 2, kc = (i & 3) * 8;
            size_t go = (size_t)(bc + n) * K + k0 + kc;
            GLDS16(&BhT[go], &Bh[(size_t)i * 8]);
            GLDS16(&BlT[go], &Bl[(size_t)i * 8]);
        }
        __syncthreads();

        half8 af[FM];
        #pragma unroll
        for (int mi = 0; mi < FM; ++mi) {
            int row = wm + mi * 16 + l16;
            af[mi] = *(const half8*)&Ah[row * 32 + quad * 8];
        }
        #pragma unroll
        for (int ni = 0; ni < FN; ++ni) {
            int row = wn + ni * 16 + l16;
            half8 bfh = *(const half8*)&Bh[row * 32 + quad * 8];
            half8 bfl = *(const half8*)&Bl[row * 32 + quad * 8];
            #pragma unroll
            for (int mi = 0; mi < FM; ++mi) {
                acc[mi][ni] = __builtin_amdgcn_mfma_f32_16x16x32_f16(af[mi], bfh, acc[mi][ni], 0, 0, 0);
                acc[mi][ni] = __builtin_amdgcn_mfma_f32_16x16x32_f16(af[mi], bfl, acc[mi][ni], 0, 0, 0);
            }
        }
        __syncthreads();
    }

    #pragma unroll
    for (int mi = 0; mi < FM; ++mi) {
        #pragma unroll
        for (int ni = 0; ni < FN; ++ni) {
            int gc = bc + wn + ni * 16 + l16;
            #pragma unroll
            for (int r = 0; r < 4; ++r) {
                int gr = br + wm + mi * 16 + quad * 4 + r;
                if (gr < N) store_out(&C[(size_t)gr * Mst + gc], acc[mi][ni][r]);
            }
        }
    }

    // ---- fused logits ----
    float aSv[FN], aDv[FN];
    #pragma unroll
    for (int ni = 0; ni < FN; ++ni) {
        int gc = bc + wn + ni * 16 + l16;
        bool ok = gc < M;
        aSv[ni] = ok ? a_s[gc] : 0.f;
        aDv[ni] = ok ? a_d[gc] : 0.f;
    }
    if (LMODE == 1) {
        #pragma unroll
        for (int mi = 0; mi < FM; ++mi) {
            #pragma unroll
            for (int r = 0; r < 4; ++r) {
                float p1a = acc[mi][0][r] * aSv[0] + acc[mi][1][r] * aSv[1];
                float p1b = acc[mi][2][r] * aSv[2] + acc[mi][3][r] * aSv[3];
                float p2a = acc[mi][0][r] * aDv[0] + acc[mi][1][r] * aDv[1];
                float p2b = acc[mi][2][r] * aDv[2] + acc[mi][3][r] * aDv[3];
                #pragma unroll
                for (int off = 1; off < 16; off <<= 1) {
                    p1a += __shfl_xor(p1a, off);
                    p1b += __shfl_xor(p1b, off);
                    p2a += __shfl_xor(p2a, off);
                    p2b += __shfl_xor(p2b, off);
                }
                if (l16 == 0) {
                    int gr = br + wm + mi * 16 + quad * 4 + r;
                    if (gr < N) {
                        int hb = (bc + wn) >> 5;
                        alS[gr * 8 + hb]     = p1a;
                        alS[gr * 8 + hb + 1] = p1b;
                        alD[gr * 8 + hb]     = p2a;
                        alD[gr * 8 + hb + 1] = p2b;
                    }
                }
            }
        }
    } else {
        #pragma unroll
        for (int mi = 0; mi < FM; ++mi) {
            #pragma unroll
            for (int r = 0; r < 4; ++r) {
                float p1 = acc[mi][0][r] * aSv[0] + acc[mi][1][r] * aSv[1]
                         + acc[mi][2][r] * aSv[2] + acc[mi][3][r] * aSv[3];
                float p2 = acc[mi][0][r] * aDv[0] + acc[mi][1][r] * aDv[1]
                         + acc[mi][2][r] * aDv[2] + acc[mi][3][r] * aDv[3];
                #pragma unroll
                for (int off = 1; off < 16; off <<= 1) {
                    p1 += __shfl_xor(p1, off);
                    p2 += __shfl_xor(p2, off);
                }
                if (l16 == 0) {
                    int gr = br + wm + mi * 16 + quad * 4 + r;
                    if (gr < N) { alS[gr] = p1; alD[gr] = p2; }
                }
            }
        }
    }
}

// ================= fused per-node softmax + aggregation =================
// H=8, C=32. One wave per node. Unchanged (control): pinned at per-CU
// MSHR x LLC-latency ceiling ~3.9 TB/s, FETCH ~92% compulsory.
__global__ __launch_bounds__(256) void node_aggr8_k(
    const int* __restrict__ rowptr, const int* __restrict__ csr_src,
    const float* __restrict__ alS, const float* __restrict__ alD,
    const __half* __restrict__ xh, const float* __restrict__ bias,
    __half* __restrict__ out, int N, int do_elu) {
    __shared__ int    lsrc[4][64];
    __shared__ __half lalpha[4][64 * 8];
    const int wv = threadIdx.x >> 6;
    int wid = (blockIdx.x * 256 + threadIdx.x) >> 6;
    int lane = threadIdx.x & 63;
    if (wid >= N) return;
    const int d = wid;
    const int beg = rowptr[d], end = rowptr[d + 1];
    const int deg = end - beg;
    const int dcap = deg < 64 ? deg : 64;

    const int h = lane & 7, esub = lane >> 3;
    const float aDh = alD[d * 8 + h];

    const int nch = (deg + 7) >> 3;

    float exv[8] = {};
    float s = 0.f;
    #pragma unroll
    for (int c = 0; c < 8; ++c) {
        int sl = c * 8 + esub;
        int e = beg + sl;
        if (e < end) {
            int src = csr_src[e];
            float ev = alS[src * 8 + h] + aDh;
            ev = ev > 0.f ? ev : 0.2f * ev;
            float ex = __expf(fminf(ev, 30.f));
            if (h == 0) lsrc[wv][sl] = src;
            exv[c] = ex;
            s += ex;
        }
    }
    for (int c = 8; c < nch; ++c) {      // overflow (deg>64): sum only
        int e = beg + c * 8 + esub;
        if (e < end) {
            int src = csr_src[e];
            float ev = alS[src * 8 + h] + aDh;
            ev = ev > 0.f ? ev : 0.2f * ev;
            s += __expf(fminf(ev, 30.f));
        }
    }
    #pragma unroll
    for (int off = 8; off < 64; off <<= 1) s += __shfl_xor(s, off);

    float rsl = 1.f / s;
    #pragma unroll
    for (int c = 0; c < 8; ++c) {
        int sl = c * 8 + esub;
        if (sl < dcap) lalpha[wv][sl * 8 + h] = __float2half(exv[c] * rsl);
    }

    const int g = lane & 31;              // channel group: channels g*8..g*8+7
    const int hh = g >> 2;                // head of this channel group
    const int p = lane >> 5;              // edge parity
    const float rs = __shfl(rsl, hh);     // only needed by the overflow path

    const char* xb = (const char*)xh;
    const unsigned goff = (unsigned)(g << 4);   // byte offset within a 512B row

    const int T = (dcap + 1) >> 1;        // pair-steps over cached edges (T>=1)
    __half2 a2q[4];
    float4 rq[4];
    __half2 hacc[4] = {};

    #pragma unroll
    for (int i = 0; i < 4; ++i) {
        int e0 = 2 * i + p;
        int idx = e0 < dcap ? e0 : dcap - 1;
        int sv = lsrc[wv][idx];
        ushort_t ub = __half_as_ushort(lalpha[wv][idx * 8 + hh]);
        if (e0 >= dcap) ub = 0;
        a2q[i] = __half2half2(__ushort_as_half(ub));
        rq[i] = *(const float4*)(xb + (((unsigned)sv << 9) + goff));
    }

    #define PROC8(i)                                                        \
    {                                                                       \
        float4 raw = rq[i];                                                 \
        __half2 a2 = a2q[i];                                                \
        int e0 = 2 * (t + 4 + (i)) + p;                                     \
        ushort_t ub = 0;                                                    \
        if (e0 < dcap) {                                                    \
            int srcn = lsrc[wv][e0];                                        \
            ub = __half_as_ushort(lalpha[wv][e0 * 8 + hh]);                 \
            rq[i] = *(const float4*)(xb + (((unsigned)srcn << 9) + goff));  \
        }                                                                   \
        a2q[i] = __half2half2(__ushort_as_half(ub));                        \
        const __half2* hp = (const __half2*)&raw;                           \
        hacc[0] = __hfma2(hp[0], a2, hacc[0]);                              \
        hacc[1] = __hfma2(hp[1], a2, hacc[1]);                              \
        hacc[2] = __hfma2(hp[2], a2, hacc[2]);                              \
        hacc[3] = __hfma2(hp[3], a2, hacc[3]);                              \
    }
    #define TAIL8(i)                                                        \
    {                                                                       \
        float4 raw = rq[i];                                                 \
        __half2 a2 = a2q[i];                                                \
        const __half2* hp = (const __half2*)&raw;                           \
        hacc[0] = __hfma2(hp[0], a2, hacc[0]);                              \
        hacc[1] = __hfma2(hp[1], a2, hacc[1]);                              \
        hacc[2] = __hfma2(hp[2], a2, hacc[2]);                              \
        hacc[3] = __hfma2(hp[3], a2, hacc[3]);                              \
    }
    int t = 0;
    for (; t + 4 <= T; t += 4) { PROC8(0) PROC8(1) PROC8(2) PROC8(3) }
    {
        int rem = T - t;   // 0..3, wave-uniform
        if (rem > 0) { TAIL8(0) if (rem > 1) { TAIL8(1) if (rem > 2) TAIL8(2) } }
    }
    #undef PROC8
    #undef TAIL8

    for (int c = 8; c < nch; ++c) {
        int base = beg + c * 8;
        int e = base + esub;
        int src_l = 0; float ex_l = 0.f;
        if (e < end) {
            src_l = csr_src[e];
            float ev = alS[src_l * 8 + h] + aDh;
            ev = ev > 0.f ? ev : 0.2f * ev;
            ex_l = __expf(fminf(ev, 30.f));
        }
        int cnt = end - base; if (cnt > 8) cnt = 8;
        int steps = (cnt + 1) >> 1;
        for (int t2 = 0; t2 < steps; ++t2) {
            int j = t2 * 2 + p;
            int jc = j < cnt ? j : (cnt - 1);
            int src = __shfl(src_l, jc * 8);
            float af = __shfl(ex_l, jc * 8 + hh) * rs;
            if (j >= cnt) af = 0.f;
            __half2 a2 = __float2half2_rn(af);
            const float4 raw = *(const float4*)(xb + (((unsigned)src << 9) + goff));
            const __half2* hp = (const __half2*)&raw;
            hacc[0] = __hfma2(hp[0], a2, hacc[0]);
            hacc[1] = __hfma2(hp[1], a2, hacc[1]);
            hacc[2] = __hfma2(hp[2], a2, hacc[2]);
            hacc[3] = __hfma2(hp[3], a2, hacc[3]);
        }
    }

    #pragma unroll
    for (int k = 0; k < 4; ++k) {
        int vi = __shfl_xor(*(int*)&hacc[k], 32);
        hacc[k] = __hadd2(hacc[k], *(__half2*)&vi);
    }

    if (p == 0) {
        float2 f0 = __half22float2(hacc[0]);
        float2 f1 = __half22float2(hacc[1]);
        float2 f2 = __half22float2(hacc[2]);
        float2 f3 = __half22float2(hacc[3]);
        const float4 bv0 = *(const float4*)&bias[g * 8];
        const float4 bv1 = *(const float4*)&bias[g * 8 + 4];
        float o[8];
        o[0] = f0.x + bv0.x; o[1] = f0.y + bv0.y;
        o[2] = f1.x + bv0.z; o[3] = f1.y + bv0.w;
        o[4] = f2.x + bv1.x; o[5] = f2.y + bv1.y;
        o[6] = f3.x + bv1.z; o[7] = f3.y + bv1.w;
        if (do_elu) {
            #pragma unroll
            for (int k = 0; k < 8; ++k) o[k] = o[k] > 0.f ? o[k] : (__expf(o[k]) - 1.f);
        }
        float4 st;
        ((__half2*)&st)[0] = __floats2half2_rn(o[0], o[1]);
        ((__half2*)&st)[1] = __floats2half2_rn(o[2], o[3]);
        ((__half2*)&st)[2] = __floats2half2_rn(o[4], o[5]);
        ((__half2*)&st)[3] = __floats2half2_rn(o[6], o[7]);
        *(float4*)(out + ((size_t)d << 8) + g * 8) = st;
    }
}

// H=1, C=40. One wave per node.
// R5: x2h rows padded 40->64 ch (128B; GEMM writes exact zeros in the pad) ->
// 4 edges/step (16 lanes x 8B each), halving the serial step count (T 9->5
// at deg~17). Lanes q>=10 accumulate pad zeros and never write.
__global__ __launch_bounds__(256) void node_aggr1_k(
    const int* __restrict__ rowptr, const int* __restrict__ csr_src,
    const float* __restrict__ alS, const float* __restrict__ alD,
    const __half* __restrict__ xh2, const float* __restrict__ bias,
    float* __restrict__ out, int N) {
    __shared__ int   lsrc1[4][64];
    __shared__ float lal1[4][64];
    const int wv = threadIdx.x >> 6;
    int wid = (blockIdx.x * 256 + threadIdx.x) >> 6;
    int lane = threadIdx.x & 63;
    if (wid >= N) return;
    const int d = wid;
    const int beg = rowptr[d], end = rowptr[d + 1];
    const int deg = end - beg;
    const int dcap = deg < 64 ? deg : 64;
    const float aD = alD[d];

    float ex0 = 0.f;
    {
        int e = beg + lane;
        if (e < end) {
            int src0 = csr_src[e];
            float ev = alS[src0] + aD;
            ev = ev > 0.f ? ev : 0.2f * ev;
            ex0 = __expf(fminf(ev, 30.f));
            lsrc1[wv][lane] = src0;
        }
    }
    float s = ex0;
    for (int e = beg + 64 + lane; e < end; e += 64) {
        int src = csr_src[e];
        float ev = alS[src] + aD;
        ev = ev > 0.f ? ev : 0.2f * ev;
        s += __expf(fminf(ev, 30.f));
    }
    #pragma unroll
    for (int off = 1; off < 64; off <<= 1) s += __shfl_xor(s, off);
    const float rs = 1.f / s;
    if (lane < dcap) lal1[wv][lane] = ex0 * rs;

    const int p = lane >> 4;              // edge slot 0..3
    const int q = lane & 15;              // 8B chunk within the 128B row
    const unsigned qb = (unsigned)(q << 3);
    const char* xb2 = (const char*)xh2;

    const int T = (dcap + 3) >> 2;        // 4-edge steps (T>=1)
    float alq[4];
    float2 rq1[4];
    float a0 = 0.f, a1 = 0.f, a2 = 0.f, a3 = 0.f;

    #pragma unroll
    for (int i = 0; i < 4; ++i) {
        int e0 = 4 * i + p;
        int idx = e0 < dcap ? e0 : dcap - 1;
        int sv = lsrc1[wv][idx];
        float av = lal1[wv][idx];
        alq[i] = e0 < dcap ? av : 0.f;
        rq1[i] = *(const float2*)(xb2 + (((unsigned)sv << 7) + qb));
    }

    #define PROC1(i)                                                        \
    {                                                                       \
        float2 raw = rq1[i];                                                \
        float al = alq[i];                                                  \
        int e0 = 4 * (t + 4 + (i)) + p;                                     \
        float an = 0.f;                                                     \
        if (e0 < dcap) {                                                    \
            int sv = lsrc1[wv][e0];                                         \
            an = lal1[wv][e0];                                              \
            rq1[i] = *(const float2*)(xb2 + (((unsigned)sv << 7) + qb));    \
        }                                                                   \
        alq[i] = an;                                                        \
        float2 lo = __half22float2(((const __half2*)&raw)[0]);              \
        float2 hi = __half22float2(((const __half2*)&raw)[1]);              \
        a0 += lo.x * al; a1 += lo.y * al;                                   \
        a2 += hi.x * al; a3 += hi.y * al;                                   \
    }
    #define TAIL1(i)                                                        \
    {                                                                       \
        float2 raw = rq1[i];                                                \
        float al = alq[i];                                                  \
        float2 lo = __half22float2(((const __half2*)&raw)[0]);              \
        float2 hi = __half22float2(((const __half2*)&raw)[1]);              \
        a0 += lo.x * al; a1 += lo.y * al;                                   \
        a2 += hi.x * al; a3 += hi.y * al;                                   \
    }
    int t = 0;
    for (; t + 4 <= T; t += 4) { PROC1(0) PROC1(1) PROC1(2) PROC1(3) }
    {
        int rem = T - t;
        if (rem > 0) { TAIL1(0) if (rem > 1) { TAIL1(1) if (rem > 2) TAIL1(2) } }
    }
    #undef PROC1
    #undef TAIL1

    // overflow (deg > 64): refill LDS per 64-edge chunk, 4-edge steps
    for (int eb = beg + 64; eb < end; eb += 64) {
        int e = eb + lane;
        int cnt = end - eb; if (cnt > 64) cnt = 64;
        if (e < end) {
            int srcl = csr_src[e];
            float ev = alS[srcl] + aD;
            ev = ev > 0.f ? ev : 0.2f * ev;
            lsrc1[wv][lane] = srcl;
            lal1[wv][lane] = __expf(fminf(ev, 30.f)) * rs;
        }
        int T2 = (cnt + 3) >> 2;
        for (int t2 = 0; t2 < T2; ++t2) {
            int e0 = 4 * t2 + p;
            float al = 0.f;
            int sv = lsrc1[wv][0];
            if (e0 < cnt) { sv = lsrc1[wv][e0]; al = lal1[wv][e0]; }
            float2 raw = *(const float2*)(xb2 + (((unsigned)sv << 7) + qb));
            float2 lo = __half22float2(((const __half2*)&raw)[0]);
            float2 hi = __half22float2(((const __half2*)&raw)[1]);
            a0 += lo.x * al; a1 += lo.y * al;
            a2 += hi.x * al; a3 += hi.y * al;
        }
    }

    // merge the 4 edge slots (lane^16, lane^32)
    a0 += __shfl_xor(a0, 16); a0 += __shfl_xor(a0, 32);
    a1 += __shfl_xor(a1, 16); a1 += __shfl_xor(a1, 32);
    a2 += __shfl_xor(a2, 16); a2 += __shfl_xor(a2, 32);
    a3 += __shfl_xor(a3, 16); a3 += __shfl_xor(a3, 32);

    if (p == 0 && q < 10) {
        const float4 bv = *(const float4*)&bias[q * 4];
        float4 st = make_float4(a0 + bv.x, a1 + bv.y, a2 + bv.z, a3 + bv.w);
        *(float4*)&out[(size_t)d * 40 + q * 4] = st;
    }
}

extern "C" void kernel_launch(void* const* d_in, const int* in_sizes, int n_in,
                              void* d_out, int out_size, void* d_ws, size_t ws_size,
                              hipStream_t stream) {
    const float* feat = (const float*)d_in[0];
    const int*   ei   = (const int*)d_in[1];
    const float* W0   = (const float*)d_in[2];
    const float* a0s  = (const float*)d_in[3];
    const float* a0d  = (const float*)d_in[4];
    const float* b0   = (const float*)d_in[5];
    const float* W1   = (const float*)d_in[6];
    const float* a1s  = (const float*)d_in[7];
    const float* a1d  = (const float*)d_in[8];
    const float* b1   = (const float*)d_in[9];
    const float* W2   = (const float*)d_in[10];
    const float* a2s  = (const float*)d_in[11];
    const float* a2d  = (const float*)d_in[12];
    const float* b2   = (const float*)d_in[13];
    float* out = (float*)d_out;

    const int N = in_sizes[0] / 128;   // 100000
    const int E = in_sizes[1] / 2;     // 1600000
    const int Etot = E + N;

    // workspace layout (~130 MB total)
    __half* hbuf = (__half*)d_ws;                     // N*256 fp16 (aggr out / gemm A)
    __half* xh   = hbuf + (size_t)N * 256;            // N*256 fp16 (gemm out; CSR staging alias)
    __half* x2h  = xh + (size_t)N * 256;              // N*64 fp16 (layer-2 gemm out, padded)
    float*  alS  = (float*)(x2h + (size_t)N * 64);    // N*8
    float*  alD  = alS + (size_t)N * 8;               // N*8
    int* rowptr   = (int*)(alD + (size_t)N * 8);      // N+1
    int* gtot     = rowptr + N + 1;                   // 512 (bucket counts)
    int* boff     = gtot + 512;                       // 513 (bucket offsets)
    int* gcur     = boff + 513;                       // 512 (bucket cursors)
    int* csr_src  = gcur + 512;                       // Etot
    int* flag     = csr_src + Etot;                   // 1
    // pre-split transposed weights (16B aligned)
    uintptr_t wsp = ((uintptr_t)(flag + 1) + 15) & ~(uintptr_t)15;
    ushort_t* w0h = (ushort_t*)wsp;                   // 256*128
    ushort_t* w0l = w0h + 256 * 128;
    ushort_t* w1h = w0l + 256 * 128;                  // 256*256
    ushort_t* w1l = w1h + 256 * 256;
    ushort_t* w2h = w1l + 256 * 256;                  // 64*256
    ushort_t* w2l = w2h + 64 * 256;

    // CSR staging (dead once csr_fine_k completes; aliases xh — stream-ordered)
    u64_t* staging = (u64_t*)xh;                      // Etot*8B <= 13.7MB < 51.2MB

    // pre-split A for layer 0 (dead after L0 GEMM; aliases hbuf — stream-ordered)
    ushort_t* fh = (ushort_t*)hbuf;                   // N*128 bf16-hi
    ushort_t* fl = fh + (size_t)N * 128;              // N*128 bf16-lo

    const int B     = (N + 255) >> 8;                 // buckets of 256 nodes (<=512)
    const int nb_e4 = (Etot + 4095) / 4096;           // hist/stage grid
    const int nb_nw = (N + 3) / 4;

    // ---- CSR build (counting sort) + fused pre-split ----
    detect64_k<<<1, 256, 0, stream>>>(ei, 512, flag, gtot);   // also zeroes gtot
    csr_hist_k<<<nb_e4, 256, 0, stream>>>(ei, flag, gtot, E, Etot, N);
    csr_scanb_k<<<1, 512, 0, stream>>>(gtot, boff, gcur, B);
    csr_stage_k<<<nb_e4, 256, 0, stream>>>(ei, flag, gcur, staging, E, Etot, N);
    csr_fine_k<<<B, 256, 0, stream>>>(staging, boff, rowptr, csr_src, N, Etot);
    {
        long totalA4 = (long)N * 128;
        int nbA = (int)((totalA4 / 4 + 255) / 256);
        prep_k<<<448 + nbA, 256, 0, stream>>>(W0, W1, W2, feat,
                                              w0h, w0l, w1h, w1l, w2h, w2l,
                                              fh, fl, totalA4);
    }

    const int mb = (N + 127) / 128;

    // ---------- Layer 0: Fin=128, H=8, C=32 (pre-split bf16 A, 3-pass, glds) ----------
    mfma_gemm_k<128, 2, 2, __half, 1><<<dim3(2, mb), 256, 0, stream>>>(
        fh, fl, w0h, w0l, xh, N, 128, 256, 256, a0s, a0d, alS, alD);
    node_aggr8_k<<<nb_nw, 256, 0, stream>>>(rowptr, csr_src, alS, alD, xh, b0,
                                            hbuf, N, 1);   // h1 -> hbuf fp16 (ELU fused)

    // ---------- Layer 1: Fin=256, H=8, C=32 (fp16 A, 2-pass f16, glds) ----------
    mfma_gemm_f16_k<128, 2, 2, __half, 1><<<dim3(2, mb), 256, 0, stream>>>(
        hbuf, w1h, w1l, xh, N, 256, 256, 256, a1s, a1d, alS, alD);
    node_aggr8_k<<<nb_nw, 256, 0, stream>>>(rowptr, csr_src, alS, alD, xh, b1,
                                            hbuf, N, 1);   // h2 -> hbuf fp16 (ELU fused)

    // ---------- Layer 2: Fin=256, H=1, C=40 (fp16 A, glds, padded 64-ch out) ----------
    mfma_gemm_f16_k<64, 4, 1, __half, 2><<<dim3(1, mb), 256, 0, stream>>>(
        hbuf, w2h, w2l, x2h, N, 256, 40, 64, a2s, a2d, alS, alD);
    node_aggr1_k<<<nb_nw, 256, 0, stream>>>(rowptr, csr_src, alS, alD, x2h, b2,
                                            out, N);       // bias fused, direct to out
}